// Round 9
// baseline (251.418 us; speedup 1.0000x reference)
//
#include <hip/hip_runtime.h>

#define NXc 468
#define NYc 468
#define CANVASc (468 * 468)   // 219024
#define NPTS 400000
#define RUN 16
#define NRUNS (NPTS / RUN)    // 25000 exactly
#define GPTS ((NPTS + 255) / 256)      // 1563
#define GVOX ((CANVASc + 255) / 256)   // 856
#define GSEAM ((NRUNS + 255) / 256)    // 98

#define PCMIN_X (-74.88f)
#define PCMIN_Y (-74.88f)
#define VOX_X 0.32f
#define VOX_Y 0.32f
#define OFF_X (-74.72f)
#define OFF_Y (-74.72f)
#define OFF_Z (1.0f)

typedef __attribute__((ext_vector_type(8))) short v8s;   // 8 bf16 (4 VGPRs)
typedef __attribute__((ext_vector_type(4))) float v4f;   // MFMA acc

static_assert(sizeof(__bf16) == 2, "bf16 must be 2 bytes");

__device__ __forceinline__ int rli(int x, int p) {
    return __builtin_amdgcn_readlane(x, p);
}
__device__ __forceinline__ float rlf(float x, int p) {
    return __int_as_float(__builtin_amdgcn_readlane(__float_as_int(x), p));
}

// Native bf16 split: hi = RNE(f), lo = RNE(f - hi).
// R3 A/B: cut kB VALUBusy 37->26% (vs manual bit-twiddle RNE). Keep.
__device__ __forceinline__ void split8(const float* f, v8s& h, v8s& l) {
    #pragma unroll
    for (int i = 0; i < 8; i += 2) {
        __bf16 h0 = (__bf16)f[i];
        __bf16 h1 = (__bf16)f[i + 1];
        h[i]     = __builtin_bit_cast(short, h0);
        h[i + 1] = __builtin_bit_cast(short, h1);
        float l0 = f[i]     - (float)h0;
        float l1 = f[i + 1] - (float)h1;
        l[i]     = __builtin_bit_cast(short, (__bf16)l0);
        l[i + 1] = __builtin_bit_cast(short, (__bf16)l1);
    }
}

// Bins MUST stay bit-identical everywhere (fp32 division, no reciprocal).
__device__ __forceinline__ int voxel_cell(float x, float y, int& cx, int& cy) {
    cx = (int)floorf((x - PCMIN_X) / VOX_X);
    cy = (int)floorf((y - PCMIN_Y) / VOX_Y);
    cx = min(max(cx, 0), NXc - 1);
    cy = min(max(cy, 0), NYc - 1);
    return cy * NXc + cx;
}

// kW body: bf16 hi/lo B-fragments for W2 (4 tiles x 4 K-chunks) and W1
// (4 tiles, K=32, rows >= 11 zero). B[k][n]: n=lane&15, k=c*32+(lane>>4)*8+i.
__device__ __forceinline__ void kw_body(int tid,
                                        const float* __restrict__ W1,
                                        const float* __restrict__ W2,
                                        v8s* __restrict__ w1frag,
                                        v8s* __restrict__ w2frag) {
    if (tid < 1024) {
        int f = tid >> 6, lane = tid & 63;
        int t = f >> 2, c = f & 3;
        int q = lane >> 4, n = lane & 15;
        float v[8];
        #pragma unroll
        for (int i = 0; i < 8; i++) v[i] = W2[(c * 32 + q * 8 + i) * 64 + t * 16 + n];
        v8s h, l;
        split8(v, h, l);
        w2frag[(f * 2 + 0) * 64 + lane] = h;
        w2frag[(f * 2 + 1) * 64 + lane] = l;
    } else if (tid < 1280) {
        int f = (tid - 1024) >> 6, lane = (tid - 1024) & 63;
        int q = lane >> 4, n = lane & 15;
        float v[8];
        #pragma unroll
        for (int i = 0; i < 8; i++) {
            int k = q * 8 + i;
            v[i] = (k < 11) ? W1[k * 64 + f * 16 + n] : 0.f;
        }
        v8s h, l;
        split8(v, h, l);
        w1frag[(f * 2 + 0) * 64 + lane] = h;
        w1frag[(f * 2 + 1) * 64 + lane] = l;
    }
}

// Pass 0: per-voxel counts; tail blocks build W-fragments (dispatch merge).
__global__ __launch_bounds__(256) void k_stats(const float* __restrict__ pts,
                                               int* __restrict__ cnt,
                                               const float* __restrict__ W1,
                                               const float* __restrict__ W2,
                                               v8s* __restrict__ w1frag,
                                               v8s* __restrict__ w2frag) {
    int b = blockIdx.x;
    if (b >= GPTS) {
        kw_body((b - GPTS) * 256 + threadIdx.x, W1, W2, w1frag, w2frag);
        return;
    }
    int i = b * 256 + threadIdx.x;
    if (i >= NPTS) return;
    float x = pts[i * 5 + 0], y = pts[i * 5 + 1];
    int cx, cy;
    int fl = voxel_cell(x, y, cx, cy);
    atomicAdd(&cnt[fl], 1);
}

// Pass 1: exclusive-scan alloc -> cursor
__global__ __launch_bounds__(256) void k_alloc(const int* __restrict__ cnt,
                                               int* __restrict__ cursor,
                                               int* __restrict__ gcur) {
    int v = blockIdx.x * 256 + threadIdx.x;
    int lane = threadIdx.x & 63;
    int c = (v < CANVASc) ? cnt[v] : 0;
    int scan = c;
    #pragma unroll
    for (int off = 1; off < 64; off <<= 1) {
        int t = __shfl_up(scan, off, 64);
        if (lane >= off) scan += t;
    }
    int total = __shfl(scan, 63, 64);
    int base = 0;
    if (lane == 0 && total > 0) base = atomicAdd(gcur, total);
    base = __shfl(base, 0, 64);
    if (v < CANVASc) cursor[v] = base + scan - c;
}

// gather one point record (random 20B; only k_scatter pays this now)
__device__ __forceinline__ void gather_pt(const float* __restrict__ pts, int pi,
                                          float4& A, float& e1) {
    const float* pp = pts + (size_t)pi * 5;
    __builtin_memcpy(&A, pp, 16);   // 4B-aligned dwordx4
    e1 = pp[4];
}

// Pass 2: record scatter (R3 win) + packed cell.
__global__ __launch_bounds__(256) void k_scatter(const float* __restrict__ pts,
                                                 int* __restrict__ cursor,
                                                 float4* __restrict__ pos4,
                                                 float* __restrict__ e1b,
                                                 int* __restrict__ cellb) {
    int i = blockIdx.x * 256 + threadIdx.x;
    if (i >= NPTS) return;
    float4 A; float e1;
    gather_pt(pts, i, A, e1);
    int cx, cy;
    int fl = voxel_cell(A.x, A.y, cx, cy);
    int pos = atomicAdd(&cursor[fl], 1);
    pos4[pos] = A;
    e1b[pos] = e1;
    cellb[pos] = cx | (cy << 16);
}

// kV: per-voxel vmean + empty-row out-zeroing; tail blocks detect seam
// voxels at wave boundaries: append to slist (for kAL) + zero the OUT row
// (which only receives atomicMax in kB). v1 seam rows are plain-stored by
// kAL, so no v1 zeroing anywhere (R7).
__global__ __launch_bounds__(256) void kV(const int* __restrict__ cnt,
                                          const int* __restrict__ cursor,
                                          const float4* __restrict__ pos4,
                                          const int* __restrict__ cellb,
                                          float4* __restrict__ vmean4,
                                          float4* __restrict__ out4,
                                          int* __restrict__ scnt,
                                          int* __restrict__ slist) {
    int b = blockIdx.x;
    if (b >= GVOX) {
        int w = (b - GVOX) * 256 + threadIdx.x;   // wave index
        if (w == 0 || w >= NRUNS) return;
        int bb = w * RUN;
        int ca = cellb[bb - 1], cb = cellb[bb];
        if (ca != cb) return;                     // no voxel spans this boundary
        int cx = ca & 0xFFFF, cy = ca >> 16;
        int va = cy * NXc + cx;
        int pos = atomicAdd(scnt, 1);
        slist[pos] = va;
        float4 z = make_float4(0.f, 0.f, 0.f, 0.f);
        float4* o = out4 + (size_t)va * 16;
        #pragma unroll
        for (int i = 0; i < 16; i++) o[i] = z;
        return;
    }
    int v = b * 256 + threadIdx.x;
    if (v >= CANVASc) return;
    int c = cnt[v];
    if (c == 0) {
        float4 z = make_float4(0.f, 0.f, 0.f, 0.f);
        float4* o = out4 + (size_t)v * 16;
        #pragma unroll
        for (int i = 0; i < 16; i++) o[i] = z;
        return;
    }
    int start = cursor[v] - c;          // cursor is post-scatter = start + c
    float sx = 0.f, sy = 0.f, sz = 0.f;
    for (int i = 0; i < c; i++) {
        float4 p = pos4[start + i];
        sx += p.x; sy += p.y; sz += p.z;
    }
    float inv = 1.0f / (float)c;
    vmean4[v] = make_float4(sx * inv, sy * inv, sz * inv, 0.f);
}

// kAL (R7, replaces MFMA-kA): one wave per seam voxel. K=11 dot in f32 —
// lane j holds W1 column j; per point broadcast 11 features via readlane,
// 11 FMA + fmax. Plain-stores the full v1 row (single writer, no atomics).
__global__ __launch_bounds__(256) void kAL(const int* __restrict__ scnt,
                                           const int* __restrict__ slist,
                                           const int* __restrict__ cnt,
                                           const int* __restrict__ cursor,
                                           const float4* __restrict__ pos4,
                                           const float* __restrict__ e1b,
                                           const int* __restrict__ cellb,
                                           const float4* __restrict__ vmean4,
                                           const float* __restrict__ W1,
                                           float* __restrict__ v1) {
    int j = threadIdx.x & 63;
    int wslot = threadIdx.x >> 6;
    int nseam = scnt[0];
    float w[11];
    #pragma unroll
    for (int k = 0; k < 11; k++) w[k] = W1[k * 64 + j];
    for (int s = blockIdx.x * 4 + wslot; s < nseam; s += gridDim.x * 4) {
        int v = slist[s];
        int c = cnt[v];
        int start = cursor[v] - c;
        float vmax = 0.f;                    // relu floor
        for (int pb = 0; pb < c; pb += 64) {
            int pc = min(c - pb, 64);
            float f[11];
            #pragma unroll
            for (int k = 0; k < 11; k++) f[k] = 0.f;
            if (j < pc) {
                int idx = start + pb + j;
                float4 A = pos4[idx];
                float e1 = e1b[idx];
                int cell = cellb[idx];
                int cx = cell & 0xFFFF, cy = cell >> 16;
                float4 mv = vmean4[v];
                f[0] = A.x; f[1] = A.y; f[2] = A.z; f[3] = A.w; f[4] = e1;
                f[5] = A.x - mv.x; f[6] = A.y - mv.y; f[7] = A.z - mv.z;
                f[8] = A.x - (cx * VOX_X + OFF_X);
                f[9] = A.y - (cy * VOX_Y + OFF_Y);
                f[10] = A.z - OFF_Z;
            }
            for (int p = 0; p < pc; p++) {
                float acc = 0.f;
                #pragma unroll
                for (int k = 0; k < 11; k++)
                    acc = fmaf(rlf(f[k], p), w[k], acc);
                vmax = fmaxf(vmax, acc);
            }
        }
        v1[(size_t)v * 64 + j] = vmax;
    }
}

// Per-lane prep: lanes 0..15 read their sorted record (coalesced float4)
// + packed cell + vmean; lanes 16/17 peek neighbor cells for edge detection.
struct PtRegs {
    float4 A;
    float  e1, fcx, fcy, fcz;
    float  mx, my, mz;
    int    vx;
};
__device__ __forceinline__ PtRegs load_pt(const float4* __restrict__ pos4,
                                          const float* __restrict__ e1b,
                                          const int* __restrict__ cellb,
                                          const float4* __restrict__ vmean4,
                                          int base, int j) {
    PtRegs r;
    r.A = make_float4(0.f, 0.f, 0.f, 0.f);
    r.e1 = r.fcx = r.fcy = r.fcz = r.mx = r.my = r.mz = 0.f;
    r.vx = -1;
    int idx = -1;
    if (j < RUN) idx = base + j;
    else if (j == 16) idx = (base + RUN < NPTS) ? base + RUN : -1;
    else if (j == 17) idx = base - 1;
    if (idx >= 0) {
        int cell = cellb[idx];
        int cx = cell & 0xFFFF, cy = cell >> 16;
        int vv = cy * NXc + cx;
        r.vx = vv;
        if (j < RUN) {
            float4 A = pos4[idx];
            r.A = A;
            r.e1 = e1b[idx];
            r.fcx = A.x - (cx * VOX_X + OFF_X);
            r.fcy = A.y - (cy * VOX_Y + OFF_Y);
            r.fcz = A.z - OFF_Z;
            float4 m = vmean4[vv];
            r.mx = m.x; r.my = m.y; r.mz = m.z;
        }
    }
    return r;
}

#define PSTR 68   // LDS row stride (floats); 68 -> 2-way bank alias (free)

// Shared phase-1: features -> LDS rows -> MFMA (K=32, 12 mfma) -> relu(D) -> LDS.
// On return s_pf rows 0..15 hold relu'd pf1[p][0..63].
__device__ __forceinline__ void phase1_mfma(float (*s_pf)[PSTR], const PtRegs& P,
                                            const v8s* __restrict__ w1frag, int j) {
    if (j < RUN) {
        float* row = s_pf[j];
        row[0] = P.A.x; row[1] = P.A.y; row[2] = P.A.z; row[3] = P.A.w; row[4] = P.e1;
        row[5] = P.A.x - P.mx; row[6] = P.A.y - P.my; row[7] = P.A.z - P.mz;
        row[8] = P.fcx; row[9] = P.fcy; row[10] = P.fcz;
        #pragma unroll
        for (int t = 11; t < 16; t++) row[t] = 0.f;
    }
    __builtin_amdgcn_wave_barrier();

    const int m = j & 15, q = j >> 4;
    v8s fh = {0,0,0,0,0,0,0,0}, fl_ = {0,0,0,0,0,0,0,0};
    if (q < 2) {
        float f8[8];
        #pragma unroll
        for (int i = 0; i < 8; i++) f8[i] = s_pf[m][q * 8 + i];
        split8(f8, fh, fl_);
    }
    v4f d[4];
    #pragma unroll
    for (int t = 0; t < 4; t++) {
        v8s bh = w1frag[(t * 2 + 0) * 64 + j];
        v8s bl = w1frag[(t * 2 + 1) * 64 + j];
        v4f acc = {0.f, 0.f, 0.f, 0.f};
        acc = __builtin_amdgcn_mfma_f32_16x16x32_bf16(fh,  bh, acc, 0, 0, 0);
        acc = __builtin_amdgcn_mfma_f32_16x16x32_bf16(fl_, bh, acc, 0, 0, 0);
        acc = __builtin_amdgcn_mfma_f32_16x16x32_bf16(fh,  bl, acc, 0, 0, 0);
        d[t] = acc;
    }
    __builtin_amdgcn_wave_barrier();   // feature reads complete before overwrite
    #pragma unroll
    for (int t = 0; t < 4; t++)
        #pragma unroll
        for (int r = 0; r < 4; r++)
            s_pf[q * 4 + r][t * 16 + m] = fmaxf(d[t][r], 0.f);
    __builtin_amdgcn_wave_barrier();
}

// kB: D[p][j] = [pf1[p], v1[vox(p)]] @ W2 via MFMA -> segment max -> out.
// R6: interior lanes rebuild v1 locally from s_pf (ballot segment bounds +
// LDS fmax loop); only ext lanes read the global seam row (written by kAL).
__global__ __launch_bounds__(256) void kB(const float4* __restrict__ pos4,
                                          const float* __restrict__ e1b,
                                          const int* __restrict__ cellb,
                                          const float4* __restrict__ vmean4,
                                          const v8s* __restrict__ w1frag,
                                          const v8s* __restrict__ w2frag,
                                          const float* __restrict__ v1,
                                          float* __restrict__ out) {
    __shared__ float s_pf[4][RUN][PSTR];
    int wslot = threadIdx.x >> 6;
    int wave = blockIdx.x * 4 + wslot;
    int j = threadIdx.x & 63;
    int base = wave * RUN;

    PtRegs P = load_pt(pos4, e1b, cellb, vmean4, base, j);

    const int m = j & 15, q = j >> 4;

    const int first = rli(P.vx, 0), last = rli(P.vx, RUN - 1);
    const bool firstExt = (rli(P.vx, 17) == first);
    const bool lastExt  = (rli(P.vx, 16) == last);

    // Per-lane segment bounds for point m (ballot over run boundaries).
    int vx_m = __builtin_amdgcn_ds_bpermute(m << 2, P.vx);
    int vx_prev = __shfl_up(P.vx, 1, 64);
    unsigned long long B =
        __ballot((j < RUN) && ((j == 0) || (P.vx != vx_prev)));
    int s_seg = 63 - __builtin_clzll(B & ((2ULL << m) - 1ULL));
    int e_seg = m + 1 + (int)__builtin_ctzll((B | (1ULL << RUN)) >> (m + 1));
    const bool ext_m = (vx_m == first && firstExt) || (vx_m == last && lastExt);

    phase1_mfma(s_pf[wslot], P, w1frag, j);

    // ext lanes: issue global seam-row loads now (covered by local loop below)
    float vf[16];
    if (ext_m) {
        const float* vr = v1 + (size_t)vx_m * 64 + q * 8;
        #pragma unroll
        for (int c = 0; c < 2; c++)
            #pragma unroll
            for (int i = 0; i < 8; i++) vf[c * 8 + i] = vr[c * 32 + i];
    }

    // A-frags: chunks 0,1 = pf1 rows (lane-distinct LDS reads)
    v8s ah[4], al[4];
    #pragma unroll
    for (int c = 0; c < 2; c++) {
        float f[8];
        #pragma unroll
        for (int i = 0; i < 8; i++) f[i] = s_pf[wslot][m][c * 32 + q * 8 + i];
        split8(f, ah[c], al[c]);
    }
    // interior lanes: v1 row = local segment max over own pf1 (identical set)
    if (!ext_m) {
        #pragma unroll
        for (int i = 0; i < 16; i++) vf[i] = 0.f;
        for (int p = s_seg; p < e_seg; p++) {
            const float* row = s_pf[wslot][p];
            float4 a0 = *(const float4*)&row[q * 8];
            float4 a1 = *(const float4*)&row[q * 8 + 4];
            float4 b0 = *(const float4*)&row[32 + q * 8];
            float4 b1 = *(const float4*)&row[32 + q * 8 + 4];
            vf[0] = fmaxf(vf[0], a0.x);  vf[1] = fmaxf(vf[1], a0.y);
            vf[2] = fmaxf(vf[2], a0.z);  vf[3] = fmaxf(vf[3], a0.w);
            vf[4] = fmaxf(vf[4], a1.x);  vf[5] = fmaxf(vf[5], a1.y);
            vf[6] = fmaxf(vf[6], a1.z);  vf[7] = fmaxf(vf[7], a1.w);
            vf[8] = fmaxf(vf[8], b0.x);  vf[9] = fmaxf(vf[9], b0.y);
            vf[10] = fmaxf(vf[10], b0.z); vf[11] = fmaxf(vf[11], b0.w);
            vf[12] = fmaxf(vf[12], b1.x); vf[13] = fmaxf(vf[13], b1.y);
            vf[14] = fmaxf(vf[14], b1.z); vf[15] = fmaxf(vf[15], b1.w);
        }
    }
    // chunks 2,3 = v1 row (segment-constant: rides inside the acc)
    split8(vf + 0, ah[2], al[2]);
    split8(vf + 8, ah[3], al[3]);
    __builtin_amdgcn_wave_barrier();   // A reads done before D overwrites s_pf

    #pragma unroll
    for (int t = 0; t < 4; t++) {
        v8s bh[4], bl[4];
        #pragma unroll
        for (int c = 0; c < 4; c++) {
            bh[c] = w2frag[((t * 4 + c) * 2 + 0) * 64 + j];
            bl[c] = w2frag[((t * 4 + c) * 2 + 1) * 64 + j];
        }
        v4f acc = {0.f, 0.f, 0.f, 0.f};
        #pragma unroll
        for (int c = 0; c < 4; c++) {
            acc = __builtin_amdgcn_mfma_f32_16x16x32_bf16(ah[c], bh[c], acc, 0, 0, 0);
            acc = __builtin_amdgcn_mfma_f32_16x16x32_bf16(al[c], bh[c], acc, 0, 0, 0);
            acc = __builtin_amdgcn_mfma_f32_16x16x32_bf16(ah[c], bl[c], acc, 0, 0, 0);
        }
        #pragma unroll
        for (int r = 0; r < 4; r++) s_pf[wslot][q * 4 + r][t * 16 + m] = acc[r];
    }
    __builtin_amdgcn_wave_barrier();

    int vprev = first;
    float smax = -3.4e38f;
    for (int p = 0; p < RUN; p++) {
        int vp = rli(P.vx, p);
        if (vp != vprev) {
            float r = fmaxf(smax, 0.f);
            size_t o = (size_t)vprev * 64 + j;
            bool ua = (vprev == first && firstExt) || (vprev == last && lastExt);
            if (ua) atomicMax((int*)out + o, __float_as_int(r));
            else out[o] = r;
            vprev = vp; smax = -3.4e38f;
        }
        smax = fmaxf(smax, s_pf[wslot][p][j]);
    }
    {
        float r = fmaxf(smax, 0.f);
        size_t o = (size_t)vprev * 64 + j;
        bool ua = (vprev == first && firstExt) || (vprev == last && lastExt);
        if (ua) atomicMax((int*)out + o, __float_as_int(r));
        else out[o] = r;
    }
}

extern "C" void kernel_launch(void* const* d_in, const int* in_sizes, int n_in,
                              void* d_out, int out_size, void* d_ws, size_t ws_size,
                              hipStream_t stream) {
    const float* pts = (const float*)d_in[0];
    const float* W1  = (const float*)d_in[1];
    const float* W2  = (const float*)d_in[2];
    float* out = (float*)d_out;

    float4* vmean4 = (float4*)d_ws;                         // CANVAS float4
    float*  v1     = (float*)(vmean4 + CANVASc);            // CANVAS*64
    float4* pos4   = (float4*)(v1 + (size_t)CANVASc * 64);  // NPTS float4
    float*  e1b    = (float*)(pos4 + NPTS);                 // NPTS
    int*    cellb  = (int*)(e1b + NPTS);                    // NPTS
    v8s*    w2frag = (v8s*)(cellb + NPTS);                  // 2048 v8s
    v8s*    w1frag = w2frag + 2048;                         // 512 v8s
    int*    cnt    = (int*)(w1frag + 512);                  // CANVAS
    int*    gcur   = cnt + CANVASc;                         // 1
    int*    scnt   = gcur + 1;                              // 1
    int*    slist  = scnt + 1;                              // NRUNS
    int*    cursor = slist + NRUNS;                         // CANVAS

    hipMemsetAsync(cnt, 0, (size_t)(CANVASc + 2) * 4, stream);   // cnt+gcur+scnt

    k_stats  <<<GPTS + 5, 256, 0, stream>>>(pts, cnt, W1, W2, w1frag, w2frag);
    k_alloc  <<<GVOX, 256, 0, stream>>>(cnt, cursor, gcur);
    k_scatter<<<GPTS, 256, 0, stream>>>(pts, cursor, pos4, e1b, cellb);
    kV       <<<GVOX + GSEAM, 256, 0, stream>>>(cnt, cursor, pos4, cellb,
                                                vmean4, (float4*)out, scnt, slist);
    kAL      <<<256, 256, 0, stream>>>(scnt, slist, cnt, cursor, pos4, e1b,
                                       cellb, vmean4, W1, v1);
    kB       <<<NRUNS / 4, 256, 0, stream>>>(pos4, e1b, cellb, vmean4, w1frag,
                                             w2frag, v1, out);
}

// Round 10
// 233.966 us; speedup vs baseline: 1.0746x; 1.0746x over previous
//
#include <hip/hip_runtime.h>

#define NXc 468
#define NYc 468
#define CANVASc (468 * 468)   // 219024
#define NPTS 400000
#define RUN 16
#define NRUNS (NPTS / RUN)    // 25000 exactly
#define GPTS ((NPTS + 255) / 256)      // 1563
#define GVOX ((CANVASc + 255) / 256)   // 856
#define GSEAM ((NRUNS + 255) / 256)    // 98

#define PCMIN_X (-74.88f)
#define PCMIN_Y (-74.88f)
#define VOX_X 0.32f
#define VOX_Y 0.32f
#define OFF_X (-74.72f)
#define OFF_Y (-74.72f)
#define OFF_Z (1.0f)

typedef __attribute__((ext_vector_type(8))) short v8s;   // 8 bf16 (4 VGPRs)
typedef __attribute__((ext_vector_type(4))) float v4f;   // MFMA acc

static_assert(sizeof(__bf16) == 2, "bf16 must be 2 bytes");

__device__ __forceinline__ int rli(int x, int p) {
    return __builtin_amdgcn_readlane(x, p);
}
__device__ __forceinline__ float rlf(float x, int p) {
    return __int_as_float(__builtin_amdgcn_readlane(__float_as_int(x), p));
}

// Native bf16 split: hi = RNE(f), lo = RNE(f - hi).
// R3 A/B: cut kB VALUBusy 37->26% (vs manual bit-twiddle RNE). Keep.
__device__ __forceinline__ void split8(const float* f, v8s& h, v8s& l) {
    #pragma unroll
    for (int i = 0; i < 8; i += 2) {
        __bf16 h0 = (__bf16)f[i];
        __bf16 h1 = (__bf16)f[i + 1];
        h[i]     = __builtin_bit_cast(short, h0);
        h[i + 1] = __builtin_bit_cast(short, h1);
        float l0 = f[i]     - (float)h0;
        float l1 = f[i + 1] - (float)h1;
        l[i]     = __builtin_bit_cast(short, (__bf16)l0);
        l[i + 1] = __builtin_bit_cast(short, (__bf16)l1);
    }
}

// Bins MUST stay bit-identical everywhere (fp32 division, no reciprocal).
__device__ __forceinline__ int voxel_cell(float x, float y, int& cx, int& cy) {
    cx = (int)floorf((x - PCMIN_X) / VOX_X);
    cy = (int)floorf((y - PCMIN_Y) / VOX_Y);
    cx = min(max(cx, 0), NXc - 1);
    cy = min(max(cy, 0), NYc - 1);
    return cy * NXc + cx;
}

// kW body: bf16 hi/lo B-fragments for W2 (4 tiles x 4 K-chunks) and W1
// (4 tiles, K=32, rows >= 11 zero). B[k][n]: n=lane&15, k=c*32+(lane>>4)*8+i.
__device__ __forceinline__ void kw_body(int tid,
                                        const float* __restrict__ W1,
                                        const float* __restrict__ W2,
                                        v8s* __restrict__ w1frag,
                                        v8s* __restrict__ w2frag) {
    if (tid < 1024) {
        int f = tid >> 6, lane = tid & 63;
        int t = f >> 2, c = f & 3;
        int q = lane >> 4, n = lane & 15;
        float v[8];
        #pragma unroll
        for (int i = 0; i < 8; i++) v[i] = W2[(c * 32 + q * 8 + i) * 64 + t * 16 + n];
        v8s h, l;
        split8(v, h, l);
        w2frag[(f * 2 + 0) * 64 + lane] = h;
        w2frag[(f * 2 + 1) * 64 + lane] = l;
    } else if (tid < 1280) {
        int f = (tid - 1024) >> 6, lane = (tid - 1024) & 63;
        int q = lane >> 4, n = lane & 15;
        float v[8];
        #pragma unroll
        for (int i = 0; i < 8; i++) {
            int k = q * 8 + i;
            v[i] = (k < 11) ? W1[k * 64 + f * 16 + n] : 0.f;
        }
        v8s h, l;
        split8(v, h, l);
        w1frag[(f * 2 + 0) * 64 + lane] = h;
        w1frag[(f * 2 + 1) * 64 + lane] = l;
    }
}

// Pass 0: per-voxel counts; tail blocks build W-fragments (dispatch merge).
__global__ __launch_bounds__(256) void k_stats(const float* __restrict__ pts,
                                               int* __restrict__ cnt,
                                               const float* __restrict__ W1,
                                               const float* __restrict__ W2,
                                               v8s* __restrict__ w1frag,
                                               v8s* __restrict__ w2frag) {
    int b = blockIdx.x;
    if (b >= GPTS) {
        kw_body((b - GPTS) * 256 + threadIdx.x, W1, W2, w1frag, w2frag);
        return;
    }
    int i = b * 256 + threadIdx.x;
    if (i >= NPTS) return;
    float x = pts[i * 5 + 0], y = pts[i * 5 + 1];
    int cx, cy;
    int fl = voxel_cell(x, y, cx, cy);
    atomicAdd(&cnt[fl], 1);
}

// Pass 1: exclusive-scan alloc -> cursor
__global__ __launch_bounds__(256) void k_alloc(const int* __restrict__ cnt,
                                               int* __restrict__ cursor,
                                               int* __restrict__ gcur) {
    int v = blockIdx.x * 256 + threadIdx.x;
    int lane = threadIdx.x & 63;
    int c = (v < CANVASc) ? cnt[v] : 0;
    int scan = c;
    #pragma unroll
    for (int off = 1; off < 64; off <<= 1) {
        int t = __shfl_up(scan, off, 64);
        if (lane >= off) scan += t;
    }
    int total = __shfl(scan, 63, 64);
    int base = 0;
    if (lane == 0 && total > 0) base = atomicAdd(gcur, total);
    base = __shfl(base, 0, 64);
    if (v < CANVASc) cursor[v] = base + scan - c;
}

// gather one point record (random 20B; only k_scatter pays this now)
__device__ __forceinline__ void gather_pt(const float* __restrict__ pts, int pi,
                                          float4& A, float& e1) {
    const float* pp = pts + (size_t)pi * 5;
    __builtin_memcpy(&A, pp, 16);   // 4B-aligned dwordx4
    e1 = pp[4];
}

// Pass 2: record scatter (R3 win) + packed cell.
__global__ __launch_bounds__(256) void k_scatter(const float* __restrict__ pts,
                                                 int* __restrict__ cursor,
                                                 float4* __restrict__ pos4,
                                                 float* __restrict__ e1b,
                                                 int* __restrict__ cellb) {
    int i = blockIdx.x * 256 + threadIdx.x;
    if (i >= NPTS) return;
    float4 A; float e1;
    gather_pt(pts, i, A, e1);
    int cx, cy;
    int fl = voxel_cell(A.x, A.y, cx, cy);
    int pos = atomicAdd(&cursor[fl], 1);
    pos4[pos] = A;
    e1b[pos] = e1;
    cellb[pos] = cx | (cy << 16);
}

// kV: per-voxel vmean + empty-row out-zeroing; tail blocks detect seam
// voxels at wave boundaries: append to slist (for kAL) + zero the OUT row
// (which only receives atomicMax in kB).
__global__ __launch_bounds__(256) void kV(const int* __restrict__ cnt,
                                          const int* __restrict__ cursor,
                                          const float4* __restrict__ pos4,
                                          const int* __restrict__ cellb,
                                          float4* __restrict__ vmean4,
                                          float4* __restrict__ out4,
                                          int* __restrict__ scnt,
                                          int* __restrict__ slist) {
    int b = blockIdx.x;
    if (b >= GVOX) {
        int w = (b - GVOX) * 256 + threadIdx.x;   // wave index
        if (w == 0 || w >= NRUNS) return;
        int bb = w * RUN;
        int ca = cellb[bb - 1], cb = cellb[bb];
        if (ca != cb) return;                     // no voxel spans this boundary
        int cx = ca & 0xFFFF, cy = ca >> 16;
        int va = cy * NXc + cx;
        int pos = atomicAdd(scnt, 1);
        slist[pos] = va;
        float4 z = make_float4(0.f, 0.f, 0.f, 0.f);
        float4* o = out4 + (size_t)va * 16;
        #pragma unroll
        for (int i = 0; i < 16; i++) o[i] = z;
        return;
    }
    int v = b * 256 + threadIdx.x;
    if (v >= CANVASc) return;
    int c = cnt[v];
    if (c == 0) {
        float4 z = make_float4(0.f, 0.f, 0.f, 0.f);
        float4* o = out4 + (size_t)v * 16;
        #pragma unroll
        for (int i = 0; i < 16; i++) o[i] = z;
        return;
    }
    int start = cursor[v] - c;          // cursor is post-scatter = start + c
    float sx = 0.f, sy = 0.f, sz = 0.f;
    for (int i = 0; i < c; i++) {
        float4 p = pos4[start + i];
        sx += p.x; sy += p.y; sz += p.z;
    }
    float inv = 1.0f / (float)c;
    vmean4[v] = make_float4(sx * inv, sy * inv, sz * inv, 0.f);
}

// kAL: one wave per seam voxel. K=11 dot in f32. R9 post-mortem: at 256
// blocks (1024 waves) each wave chained ~12 seams SERIALLY -> latency-bound
// (~30 µs, regression). Fix: full-width grid, ONE seam per wave, excess
// waves exit — TLP hides the dependent-load chain.
__global__ __launch_bounds__(256) void kAL(const int* __restrict__ scnt,
                                           const int* __restrict__ slist,
                                           const int* __restrict__ cnt,
                                           const int* __restrict__ cursor,
                                           const float4* __restrict__ pos4,
                                           const float* __restrict__ e1b,
                                           const int* __restrict__ cellb,
                                           const float4* __restrict__ vmean4,
                                           const float* __restrict__ W1,
                                           float* __restrict__ v1) {
    int j = threadIdx.x & 63;
    int wslot = threadIdx.x >> 6;
    int s = blockIdx.x * 4 + wslot;
    if (s >= scnt[0]) return;
    float w[11];
    #pragma unroll
    for (int k = 0; k < 11; k++) w[k] = W1[k * 64 + j];
    int v = slist[s];
    int c = cnt[v];
    int start = cursor[v] - c;
    float vmax = 0.f;                    // relu floor
    for (int pb = 0; pb < c; pb += 64) {
        int pc = min(c - pb, 64);
        float f[11];
        #pragma unroll
        for (int k = 0; k < 11; k++) f[k] = 0.f;
        if (j < pc) {
            int idx = start + pb + j;
            float4 A = pos4[idx];
            float e1 = e1b[idx];
            int cell = cellb[idx];
            int cx = cell & 0xFFFF, cy = cell >> 16;
            float4 mv = vmean4[v];
            f[0] = A.x; f[1] = A.y; f[2] = A.z; f[3] = A.w; f[4] = e1;
            f[5] = A.x - mv.x; f[6] = A.y - mv.y; f[7] = A.z - mv.z;
            f[8] = A.x - (cx * VOX_X + OFF_X);
            f[9] = A.y - (cy * VOX_Y + OFF_Y);
            f[10] = A.z - OFF_Z;
        }
        for (int p = 0; p < pc; p++) {
            float acc = 0.f;
            #pragma unroll
            for (int k = 0; k < 11; k++)
                acc = fmaf(rlf(f[k], p), w[k], acc);
            vmax = fmaxf(vmax, acc);
        }
    }
    v1[(size_t)v * 64 + j] = vmax;
}

// Per-lane prep: lanes 0..15 read their sorted record (coalesced float4)
// + packed cell + vmean; lanes 16/17 peek neighbor cells for edge detection.
struct PtRegs {
    float4 A;
    float  e1, fcx, fcy, fcz;
    float  mx, my, mz;
    int    vx;
};
__device__ __forceinline__ PtRegs load_pt(const float4* __restrict__ pos4,
                                          const float* __restrict__ e1b,
                                          const int* __restrict__ cellb,
                                          const float4* __restrict__ vmean4,
                                          int base, int j) {
    PtRegs r;
    r.A = make_float4(0.f, 0.f, 0.f, 0.f);
    r.e1 = r.fcx = r.fcy = r.fcz = r.mx = r.my = r.mz = 0.f;
    r.vx = -1;
    int idx = -1;
    if (j < RUN) idx = base + j;
    else if (j == 16) idx = (base + RUN < NPTS) ? base + RUN : -1;
    else if (j == 17) idx = base - 1;
    if (idx >= 0) {
        int cell = cellb[idx];
        int cx = cell & 0xFFFF, cy = cell >> 16;
        int vv = cy * NXc + cx;
        r.vx = vv;
        if (j < RUN) {
            float4 A = pos4[idx];
            r.A = A;
            r.e1 = e1b[idx];
            r.fcx = A.x - (cx * VOX_X + OFF_X);
            r.fcy = A.y - (cy * VOX_Y + OFF_Y);
            r.fcz = A.z - OFF_Z;
            float4 m = vmean4[vv];
            r.mx = m.x; r.my = m.y; r.mz = m.z;
        }
    }
    return r;
}

#define PSTR 68   // LDS row stride (floats); 68 -> 2-way bank alias (free)

// Shared phase-1: features -> LDS rows -> MFMA (K=32, 12 mfma) -> relu(D) -> LDS.
// On return s_pf rows 0..15 hold relu'd pf1[p][0..63].
__device__ __forceinline__ void phase1_mfma(float (*s_pf)[PSTR], const PtRegs& P,
                                            const v8s* __restrict__ w1frag, int j) {
    if (j < RUN) {
        float* row = s_pf[j];
        row[0] = P.A.x; row[1] = P.A.y; row[2] = P.A.z; row[3] = P.A.w; row[4] = P.e1;
        row[5] = P.A.x - P.mx; row[6] = P.A.y - P.my; row[7] = P.A.z - P.mz;
        row[8] = P.fcx; row[9] = P.fcy; row[10] = P.fcz;
        #pragma unroll
        for (int t = 11; t < 16; t++) row[t] = 0.f;
    }
    __builtin_amdgcn_wave_barrier();

    const int m = j & 15, q = j >> 4;
    v8s fh = {0,0,0,0,0,0,0,0}, fl_ = {0,0,0,0,0,0,0,0};
    if (q < 2) {
        float f8[8];
        #pragma unroll
        for (int i = 0; i < 8; i++) f8[i] = s_pf[m][q * 8 + i];
        split8(f8, fh, fl_);
    }
    v4f d[4];
    #pragma unroll
    for (int t = 0; t < 4; t++) {
        v8s bh = w1frag[(t * 2 + 0) * 64 + j];
        v8s bl = w1frag[(t * 2 + 1) * 64 + j];
        v4f acc = {0.f, 0.f, 0.f, 0.f};
        acc = __builtin_amdgcn_mfma_f32_16x16x32_bf16(fh,  bh, acc, 0, 0, 0);
        acc = __builtin_amdgcn_mfma_f32_16x16x32_bf16(fl_, bh, acc, 0, 0, 0);
        acc = __builtin_amdgcn_mfma_f32_16x16x32_bf16(fh,  bl, acc, 0, 0, 0);
        d[t] = acc;
    }
    __builtin_amdgcn_wave_barrier();   // feature reads complete before overwrite
    #pragma unroll
    for (int t = 0; t < 4; t++)
        #pragma unroll
        for (int r = 0; r < 4; r++)
            s_pf[q * 4 + r][t * 16 + m] = fmaxf(d[t][r], 0.f);
    __builtin_amdgcn_wave_barrier();
}

// kB: D[p][j] = [pf1[p], v1[vox(p)]] @ W2 via MFMA -> segment max -> out.
// R6: interior lanes rebuild v1 locally from s_pf (ballot segment bounds +
// LDS fmax loop); only ext lanes read the global seam row (written by kAL).
__global__ __launch_bounds__(256) void kB(const float4* __restrict__ pos4,
                                          const float* __restrict__ e1b,
                                          const int* __restrict__ cellb,
                                          const float4* __restrict__ vmean4,
                                          const v8s* __restrict__ w1frag,
                                          const v8s* __restrict__ w2frag,
                                          const float* __restrict__ v1,
                                          float* __restrict__ out) {
    __shared__ float s_pf[4][RUN][PSTR];
    int wslot = threadIdx.x >> 6;
    int wave = blockIdx.x * 4 + wslot;
    int j = threadIdx.x & 63;
    int base = wave * RUN;

    PtRegs P = load_pt(pos4, e1b, cellb, vmean4, base, j);

    const int m = j & 15, q = j >> 4;

    const int first = rli(P.vx, 0), last = rli(P.vx, RUN - 1);
    const bool firstExt = (rli(P.vx, 17) == first);
    const bool lastExt  = (rli(P.vx, 16) == last);

    // Per-lane segment bounds for point m (ballot over run boundaries).
    int vx_m = __builtin_amdgcn_ds_bpermute(m << 2, P.vx);
    int vx_prev = __shfl_up(P.vx, 1, 64);
    unsigned long long B =
        __ballot((j < RUN) && ((j == 0) || (P.vx != vx_prev)));
    int s_seg = 63 - __builtin_clzll(B & ((2ULL << m) - 1ULL));
    int e_seg = m + 1 + (int)__builtin_ctzll((B | (1ULL << RUN)) >> (m + 1));
    const bool ext_m = (vx_m == first && firstExt) || (vx_m == last && lastExt);

    phase1_mfma(s_pf[wslot], P, w1frag, j);

    // ext lanes: issue global seam-row loads now (covered by local loop below)
    float vf[16];
    if (ext_m) {
        const float* vr = v1 + (size_t)vx_m * 64 + q * 8;
        #pragma unroll
        for (int c = 0; c < 2; c++)
            #pragma unroll
            for (int i = 0; i < 8; i++) vf[c * 8 + i] = vr[c * 32 + i];
    }

    // A-frags: chunks 0,1 = pf1 rows (lane-distinct LDS reads)
    v8s ah[4], al[4];
    #pragma unroll
    for (int c = 0; c < 2; c++) {
        float f[8];
        #pragma unroll
        for (int i = 0; i < 8; i++) f[i] = s_pf[wslot][m][c * 32 + q * 8 + i];
        split8(f, ah[c], al[c]);
    }
    // interior lanes: v1 row = local segment max over own pf1 (identical set)
    if (!ext_m) {
        #pragma unroll
        for (int i = 0; i < 16; i++) vf[i] = 0.f;
        for (int p = s_seg; p < e_seg; p++) {
            const float* row = s_pf[wslot][p];
            float4 a0 = *(const float4*)&row[q * 8];
            float4 a1 = *(const float4*)&row[q * 8 + 4];
            float4 b0 = *(const float4*)&row[32 + q * 8];
            float4 b1 = *(const float4*)&row[32 + q * 8 + 4];
            vf[0] = fmaxf(vf[0], a0.x);  vf[1] = fmaxf(vf[1], a0.y);
            vf[2] = fmaxf(vf[2], a0.z);  vf[3] = fmaxf(vf[3], a0.w);
            vf[4] = fmaxf(vf[4], a1.x);  vf[5] = fmaxf(vf[5], a1.y);
            vf[6] = fmaxf(vf[6], a1.z);  vf[7] = fmaxf(vf[7], a1.w);
            vf[8] = fmaxf(vf[8], b0.x);  vf[9] = fmaxf(vf[9], b0.y);
            vf[10] = fmaxf(vf[10], b0.z); vf[11] = fmaxf(vf[11], b0.w);
            vf[12] = fmaxf(vf[12], b1.x); vf[13] = fmaxf(vf[13], b1.y);
            vf[14] = fmaxf(vf[14], b1.z); vf[15] = fmaxf(vf[15], b1.w);
        }
    }
    // chunks 2,3 = v1 row (segment-constant: rides inside the acc)
    split8(vf + 0, ah[2], al[2]);
    split8(vf + 8, ah[3], al[3]);
    __builtin_amdgcn_wave_barrier();   // A reads done before D overwrites s_pf

    #pragma unroll
    for (int t = 0; t < 4; t++) {
        v8s bh[4], bl[4];
        #pragma unroll
        for (int c = 0; c < 4; c++) {
            bh[c] = w2frag[((t * 4 + c) * 2 + 0) * 64 + j];
            bl[c] = w2frag[((t * 4 + c) * 2 + 1) * 64 + j];
        }
        v4f acc = {0.f, 0.f, 0.f, 0.f};
        #pragma unroll
        for (int c = 0; c < 4; c++) {
            acc = __builtin_amdgcn_mfma_f32_16x16x32_bf16(ah[c], bh[c], acc, 0, 0, 0);
            acc = __builtin_amdgcn_mfma_f32_16x16x32_bf16(al[c], bh[c], acc, 0, 0, 0);
            acc = __builtin_amdgcn_mfma_f32_16x16x32_bf16(ah[c], bl[c], acc, 0, 0, 0);
        }
        #pragma unroll
        for (int r = 0; r < 4; r++) s_pf[wslot][q * 4 + r][t * 16 + m] = acc[r];
    }
    __builtin_amdgcn_wave_barrier();

    int vprev = first;
    float smax = -3.4e38f;
    for (int p = 0; p < RUN; p++) {
        int vp = rli(P.vx, p);
        if (vp != vprev) {
            float r = fmaxf(smax, 0.f);
            size_t o = (size_t)vprev * 64 + j;
            bool ua = (vprev == first && firstExt) || (vprev == last && lastExt);
            if (ua) atomicMax((int*)out + o, __float_as_int(r));
            else out[o] = r;
            vprev = vp; smax = -3.4e38f;
        }
        smax = fmaxf(smax, s_pf[wslot][p][j]);
    }
    {
        float r = fmaxf(smax, 0.f);
        size_t o = (size_t)vprev * 64 + j;
        bool ua = (vprev == first && firstExt) || (vprev == last && lastExt);
        if (ua) atomicMax((int*)out + o, __float_as_int(r));
        else out[o] = r;
    }
}

extern "C" void kernel_launch(void* const* d_in, const int* in_sizes, int n_in,
                              void* d_out, int out_size, void* d_ws, size_t ws_size,
                              hipStream_t stream) {
    const float* pts = (const float*)d_in[0];
    const float* W1  = (const float*)d_in[1];
    const float* W2  = (const float*)d_in[2];
    float* out = (float*)d_out;

    float4* vmean4 = (float4*)d_ws;                         // CANVAS float4
    float*  v1     = (float*)(vmean4 + CANVASc);            // CANVAS*64
    float4* pos4   = (float4*)(v1 + (size_t)CANVASc * 64);  // NPTS float4
    float*  e1b    = (float*)(pos4 + NPTS);                 // NPTS
    int*    cellb  = (int*)(e1b + NPTS);                    // NPTS
    v8s*    w2frag = (v8s*)(cellb + NPTS);                  // 2048 v8s
    v8s*    w1frag = w2frag + 2048;                         // 512 v8s
    int*    cnt    = (int*)(w1frag + 512);                  // CANVAS
    int*    gcur   = cnt + CANVASc;                         // 1
    int*    scnt   = gcur + 1;                              // 1
    int*    slist  = scnt + 1;                              // NRUNS
    int*    cursor = slist + NRUNS;                         // CANVAS

    hipMemsetAsync(cnt, 0, (size_t)(CANVASc + 2) * 4, stream);   // cnt+gcur+scnt

    k_stats  <<<GPTS + 5, 256, 0, stream>>>(pts, cnt, W1, W2, w1frag, w2frag);
    k_alloc  <<<GVOX, 256, 0, stream>>>(cnt, cursor, gcur);
    k_scatter<<<GPTS, 256, 0, stream>>>(pts, cursor, pos4, e1b, cellb);
    kV       <<<GVOX + GSEAM, 256, 0, stream>>>(cnt, cursor, pos4, cellb,
                                                vmean4, (float4*)out, scnt, slist);
    kAL      <<<NRUNS / 4, 256, 0, stream>>>(scnt, slist, cnt, cursor, pos4, e1b,
                                             cellb, vmean4, W1, v1);
    kB       <<<NRUNS / 4, 256, 0, stream>>>(pos4, e1b, cellb, vmean4, w1frag,
                                             w2frag, v1, out);
}

// Round 11
// 226.016 us; speedup vs baseline: 1.1124x; 1.0352x over previous
//
#include <hip/hip_runtime.h>

#define NXc 468
#define NYc 468
#define CANVASc (468 * 468)   // 219024
#define NPTS 400000
#define RUN 16
#define NRUNS (NPTS / RUN)    // 25000 exactly
#define GPTS ((NPTS + 255) / 256)      // 1563
#define GVOX ((CANVASc + 255) / 256)   // 856
#define GSEAM ((NRUNS + 255) / 256)    // 98

#define PCMIN_X (-74.88f)
#define PCMIN_Y (-74.88f)
#define VOX_X 0.32f
#define VOX_Y 0.32f
#define OFF_X (-74.72f)
#define OFF_Y (-74.72f)
#define OFF_Z (1.0f)

typedef __attribute__((ext_vector_type(8))) short v8s;   // 8 bf16 (4 VGPRs)
typedef __attribute__((ext_vector_type(4))) float v4f;   // MFMA acc

static_assert(sizeof(__bf16) == 2, "bf16 must be 2 bytes");

__device__ __forceinline__ int rli(int x, int p) {
    return __builtin_amdgcn_readlane(x, p);
}
__device__ __forceinline__ float rlf(float x, int p) {
    return __int_as_float(__builtin_amdgcn_readlane(__float_as_int(x), p));
}

// Native bf16 split: hi = RNE(f), lo = RNE(f - hi).
// R3 A/B: cut kB VALUBusy 37->26% (vs manual bit-twiddle RNE). Keep.
__device__ __forceinline__ void split8(const float* f, v8s& h, v8s& l) {
    #pragma unroll
    for (int i = 0; i < 8; i += 2) {
        __bf16 h0 = (__bf16)f[i];
        __bf16 h1 = (__bf16)f[i + 1];
        h[i]     = __builtin_bit_cast(short, h0);
        h[i + 1] = __builtin_bit_cast(short, h1);
        float l0 = f[i]     - (float)h0;
        float l1 = f[i + 1] - (float)h1;
        l[i]     = __builtin_bit_cast(short, (__bf16)l0);
        l[i + 1] = __builtin_bit_cast(short, (__bf16)l1);
    }
}

// Bins MUST stay bit-identical everywhere (fp32 division, no reciprocal).
__device__ __forceinline__ int voxel_cell(float x, float y, int& cx, int& cy) {
    cx = (int)floorf((x - PCMIN_X) / VOX_X);
    cy = (int)floorf((y - PCMIN_Y) / VOX_Y);
    cx = min(max(cx, 0), NXc - 1);
    cy = min(max(cy, 0), NYc - 1);
    return cy * NXc + cx;
}

// kW body: bf16 hi/lo B-fragments for W2 (4 tiles x 4 K-chunks) and W1
// (4 tiles, K=32, rows >= 11 zero). B[k][n]: n=lane&15, k=c*32+(lane>>4)*8+i.
__device__ __forceinline__ void kw_body(int tid,
                                        const float* __restrict__ W1,
                                        const float* __restrict__ W2,
                                        v8s* __restrict__ w1frag,
                                        v8s* __restrict__ w2frag) {
    if (tid < 1024) {
        int f = tid >> 6, lane = tid & 63;
        int t = f >> 2, c = f & 3;
        int q = lane >> 4, n = lane & 15;
        float v[8];
        #pragma unroll
        for (int i = 0; i < 8; i++) v[i] = W2[(c * 32 + q * 8 + i) * 64 + t * 16 + n];
        v8s h, l;
        split8(v, h, l);
        w2frag[(f * 2 + 0) * 64 + lane] = h;
        w2frag[(f * 2 + 1) * 64 + lane] = l;
    } else if (tid < 1280) {
        int f = (tid - 1024) >> 6, lane = (tid - 1024) & 63;
        int q = lane >> 4, n = lane & 15;
        float v[8];
        #pragma unroll
        for (int i = 0; i < 8; i++) {
            int k = q * 8 + i;
            v[i] = (k < 11) ? W1[k * 64 + f * 16 + n] : 0.f;
        }
        v8s h, l;
        split8(v, h, l);
        w1frag[(f * 2 + 0) * 64 + lane] = h;
        w1frag[(f * 2 + 1) * 64 + lane] = l;
    }
}

// Pass 0 (R10): counts + per-point RANK (the atomic's return value — free)
// + packed cell. Rank makes k_scatter atomic-free: pos = cursor[fl]+rank.
// Tail blocks build W-fragments (dispatch merge).
__global__ __launch_bounds__(256) void k_stats(const float* __restrict__ pts,
                                               int* __restrict__ cnt,
                                               int* __restrict__ rankb,
                                               int* __restrict__ cellu,
                                               const float* __restrict__ W1,
                                               const float* __restrict__ W2,
                                               v8s* __restrict__ w1frag,
                                               v8s* __restrict__ w2frag) {
    int b = blockIdx.x;
    if (b >= GPTS) {
        kw_body((b - GPTS) * 256 + threadIdx.x, W1, W2, w1frag, w2frag);
        return;
    }
    int i = b * 256 + threadIdx.x;
    if (i >= NPTS) return;
    float x = pts[i * 5 + 0], y = pts[i * 5 + 1];
    int cx, cy;
    int fl = voxel_cell(x, y, cx, cy);
    rankb[i] = atomicAdd(&cnt[fl], 1);
    cellu[i] = cx | (cy << 16);
}

// Pass 1: exclusive-scan alloc -> cursor (= segment start, never bumped now)
__global__ __launch_bounds__(256) void k_alloc(const int* __restrict__ cnt,
                                               int* __restrict__ cursor,
                                               int* __restrict__ gcur) {
    int v = blockIdx.x * 256 + threadIdx.x;
    int lane = threadIdx.x & 63;
    int c = (v < CANVASc) ? cnt[v] : 0;
    int scan = c;
    #pragma unroll
    for (int off = 1; off < 64; off <<= 1) {
        int t = __shfl_up(scan, off, 64);
        if (lane >= off) scan += t;
    }
    int total = __shfl(scan, 63, 64);
    int base = 0;
    if (lane == 0 && total > 0) base = atomicAdd(gcur, total);
    base = __shfl(base, 0, 64);
    if (v < CANVASc) cursor[v] = base + scan - c;
}

// gather one point record (coalesced-ish 20B strided read)
__device__ __forceinline__ void gather_pt(const float* __restrict__ pts, int pi,
                                          float4& A, float& e1) {
    const float* pp = pts + (size_t)pi * 5;
    __builtin_memcpy(&A, pp, 16);   // 4B-aligned dwordx4
    e1 = pp[4];
}

// Pass 2 (R10): ATOMIC-FREE record scatter. pos = cursor[fl] + rank[i].
// (R9 calibration: 400k scattered RMWs ≈ 15-20 µs — this removes one full
// scattered-atomic pass vs the old cursor-bump scatter.)
__global__ __launch_bounds__(256) void k_scatter(const float* __restrict__ pts,
                                                 const int* __restrict__ cursor,
                                                 const int* __restrict__ rankb,
                                                 const int* __restrict__ cellu,
                                                 float4* __restrict__ pos4,
                                                 float* __restrict__ e1b,
                                                 int* __restrict__ cellb) {
    int i = blockIdx.x * 256 + threadIdx.x;
    if (i >= NPTS) return;
    float4 A; float e1;
    gather_pt(pts, i, A, e1);
    int cell = cellu[i];
    int cx = cell & 0xFFFF, cy = cell >> 16;
    int fl = cy * NXc + cx;
    int pos = cursor[fl] + rankb[i];
    pos4[pos] = A;
    e1b[pos] = e1;
    cellb[pos] = cell;
}

// kV: per-voxel vmean + empty-row out-zeroing; tail blocks detect seam
// voxels at wave boundaries: append to slist (for kAL) + zero the OUT row
// (which only receives atomicMax in kB). cursor[v] is now the segment START.
__global__ __launch_bounds__(256) void kV(const int* __restrict__ cnt,
                                          const int* __restrict__ cursor,
                                          const float4* __restrict__ pos4,
                                          const int* __restrict__ cellb,
                                          float4* __restrict__ vmean4,
                                          float4* __restrict__ out4,
                                          int* __restrict__ scnt,
                                          int* __restrict__ slist) {
    int b = blockIdx.x;
    if (b >= GVOX) {
        int w = (b - GVOX) * 256 + threadIdx.x;   // wave index
        if (w == 0 || w >= NRUNS) return;
        int bb = w * RUN;
        int ca = cellb[bb - 1], cb = cellb[bb];
        if (ca != cb) return;                     // no voxel spans this boundary
        int cx = ca & 0xFFFF, cy = ca >> 16;
        int va = cy * NXc + cx;
        int pos = atomicAdd(scnt, 1);
        slist[pos] = va;
        float4 z = make_float4(0.f, 0.f, 0.f, 0.f);
        float4* o = out4 + (size_t)va * 16;
        #pragma unroll
        for (int i = 0; i < 16; i++) o[i] = z;
        return;
    }
    int v = b * 256 + threadIdx.x;
    if (v >= CANVASc) return;
    int c = cnt[v];
    if (c == 0) {
        float4 z = make_float4(0.f, 0.f, 0.f, 0.f);
        float4* o = out4 + (size_t)v * 16;
        #pragma unroll
        for (int i = 0; i < 16; i++) o[i] = z;
        return;
    }
    int start = cursor[v];              // exclusive-scan base = segment start
    float sx = 0.f, sy = 0.f, sz = 0.f;
    for (int i = 0; i < c; i++) {
        float4 p = pos4[start + i];
        sx += p.x; sy += p.y; sz += p.z;
    }
    float inv = 1.0f / (float)c;
    vmean4[v] = make_float4(sx * inv, sy * inv, sz * inv, 0.f);
}

// kAL: one wave per seam voxel (R10: full-width grid — R9's 256-block
// grid-stride serial chaining was a 30 µs latency-bound regression).
__global__ __launch_bounds__(256) void kAL(const int* __restrict__ scnt,
                                           const int* __restrict__ slist,
                                           const int* __restrict__ cnt,
                                           const int* __restrict__ cursor,
                                           const float4* __restrict__ pos4,
                                           const float* __restrict__ e1b,
                                           const int* __restrict__ cellb,
                                           const float4* __restrict__ vmean4,
                                           const float* __restrict__ W1,
                                           float* __restrict__ v1) {
    int j = threadIdx.x & 63;
    int wslot = threadIdx.x >> 6;
    int s = blockIdx.x * 4 + wslot;
    if (s >= scnt[0]) return;
    float w[11];
    #pragma unroll
    for (int k = 0; k < 11; k++) w[k] = W1[k * 64 + j];
    int v = slist[s];
    int c = cnt[v];
    int start = cursor[v];
    float vmax = 0.f;                    // relu floor
    for (int pb = 0; pb < c; pb += 64) {
        int pc = min(c - pb, 64);
        float f[11];
        #pragma unroll
        for (int k = 0; k < 11; k++) f[k] = 0.f;
        if (j < pc) {
            int idx = start + pb + j;
            float4 A = pos4[idx];
            float e1 = e1b[idx];
            int cell = cellb[idx];
            int cx = cell & 0xFFFF, cy = cell >> 16;
            float4 mv = vmean4[v];
            f[0] = A.x; f[1] = A.y; f[2] = A.z; f[3] = A.w; f[4] = e1;
            f[5] = A.x - mv.x; f[6] = A.y - mv.y; f[7] = A.z - mv.z;
            f[8] = A.x - (cx * VOX_X + OFF_X);
            f[9] = A.y - (cy * VOX_Y + OFF_Y);
            f[10] = A.z - OFF_Z;
        }
        for (int p = 0; p < pc; p++) {
            float acc = 0.f;
            #pragma unroll
            for (int k = 0; k < 11; k++)
                acc = fmaf(rlf(f[k], p), w[k], acc);
            vmax = fmaxf(vmax, acc);
        }
    }
    v1[(size_t)v * 64 + j] = vmax;
}

// Per-lane prep: lanes 0..15 read their sorted record (coalesced float4)
// + packed cell + vmean; lanes 16/17 peek neighbor cells for edge detection.
struct PtRegs {
    float4 A;
    float  e1, fcx, fcy, fcz;
    float  mx, my, mz;
    int    vx;
};
__device__ __forceinline__ PtRegs load_pt(const float4* __restrict__ pos4,
                                          const float* __restrict__ e1b,
                                          const int* __restrict__ cellb,
                                          const float4* __restrict__ vmean4,
                                          int base, int j) {
    PtRegs r;
    r.A = make_float4(0.f, 0.f, 0.f, 0.f);
    r.e1 = r.fcx = r.fcy = r.fcz = r.mx = r.my = r.mz = 0.f;
    r.vx = -1;
    int idx = -1;
    if (j < RUN) idx = base + j;
    else if (j == 16) idx = (base + RUN < NPTS) ? base + RUN : -1;
    else if (j == 17) idx = base - 1;
    if (idx >= 0) {
        int cell = cellb[idx];
        int cx = cell & 0xFFFF, cy = cell >> 16;
        int vv = cy * NXc + cx;
        r.vx = vv;
        if (j < RUN) {
            float4 A = pos4[idx];
            r.A = A;
            r.e1 = e1b[idx];
            r.fcx = A.x - (cx * VOX_X + OFF_X);
            r.fcy = A.y - (cy * VOX_Y + OFF_Y);
            r.fcz = A.z - OFF_Z;
            float4 m = vmean4[vv];
            r.mx = m.x; r.my = m.y; r.mz = m.z;
        }
    }
    return r;
}

#define PSTR 68   // LDS row stride (floats); 68 -> 2-way bank alias (free)

// Shared phase-1: features -> LDS rows -> MFMA (K=32, 12 mfma) -> relu(D) -> LDS.
// On return s_pf rows 0..15 hold relu'd pf1[p][0..63].
__device__ __forceinline__ void phase1_mfma(float (*s_pf)[PSTR], const PtRegs& P,
                                            const v8s* __restrict__ w1frag, int j) {
    if (j < RUN) {
        float* row = s_pf[j];
        row[0] = P.A.x; row[1] = P.A.y; row[2] = P.A.z; row[3] = P.A.w; row[4] = P.e1;
        row[5] = P.A.x - P.mx; row[6] = P.A.y - P.my; row[7] = P.A.z - P.mz;
        row[8] = P.fcx; row[9] = P.fcy; row[10] = P.fcz;
        #pragma unroll
        for (int t = 11; t < 16; t++) row[t] = 0.f;
    }
    __builtin_amdgcn_wave_barrier();

    const int m = j & 15, q = j >> 4;
    v8s fh = {0,0,0,0,0,0,0,0}, fl_ = {0,0,0,0,0,0,0,0};
    if (q < 2) {
        float f8[8];
        #pragma unroll
        for (int i = 0; i < 8; i++) f8[i] = s_pf[m][q * 8 + i];
        split8(f8, fh, fl_);
    }
    v4f d[4];
    #pragma unroll
    for (int t = 0; t < 4; t++) {
        v8s bh = w1frag[(t * 2 + 0) * 64 + j];
        v8s bl = w1frag[(t * 2 + 1) * 64 + j];
        v4f acc = {0.f, 0.f, 0.f, 0.f};
        acc = __builtin_amdgcn_mfma_f32_16x16x32_bf16(fh,  bh, acc, 0, 0, 0);
        acc = __builtin_amdgcn_mfma_f32_16x16x32_bf16(fl_, bh, acc, 0, 0, 0);
        acc = __builtin_amdgcn_mfma_f32_16x16x32_bf16(fh,  bl, acc, 0, 0, 0);
        d[t] = acc;
    }
    __builtin_amdgcn_wave_barrier();   // feature reads complete before overwrite
    #pragma unroll
    for (int t = 0; t < 4; t++)
        #pragma unroll
        for (int r = 0; r < 4; r++)
            s_pf[q * 4 + r][t * 16 + m] = fmaxf(d[t][r], 0.f);
    __builtin_amdgcn_wave_barrier();
}

// kB: D[p][j] = [pf1[p], v1[vox(p)]] @ W2 via MFMA -> segment max -> out.
// R6: interior lanes rebuild v1 locally from s_pf (ballot segment bounds +
// LDS fmax loop); only ext lanes read the global seam row (written by kAL).
__global__ __launch_bounds__(256) void kB(const float4* __restrict__ pos4,
                                          const float* __restrict__ e1b,
                                          const int* __restrict__ cellb,
                                          const float4* __restrict__ vmean4,
                                          const v8s* __restrict__ w1frag,
                                          const v8s* __restrict__ w2frag,
                                          const float* __restrict__ v1,
                                          float* __restrict__ out) {
    __shared__ float s_pf[4][RUN][PSTR];
    int wslot = threadIdx.x >> 6;
    int wave = blockIdx.x * 4 + wslot;
    int j = threadIdx.x & 63;
    int base = wave * RUN;

    PtRegs P = load_pt(pos4, e1b, cellb, vmean4, base, j);

    const int m = j & 15, q = j >> 4;

    const int first = rli(P.vx, 0), last = rli(P.vx, RUN - 1);
    const bool firstExt = (rli(P.vx, 17) == first);
    const bool lastExt  = (rli(P.vx, 16) == last);

    // Per-lane segment bounds for point m (ballot over run boundaries).
    int vx_m = __builtin_amdgcn_ds_bpermute(m << 2, P.vx);
    int vx_prev = __shfl_up(P.vx, 1, 64);
    unsigned long long B =
        __ballot((j < RUN) && ((j == 0) || (P.vx != vx_prev)));
    int s_seg = 63 - __builtin_clzll(B & ((2ULL << m) - 1ULL));
    int e_seg = m + 1 + (int)__builtin_ctzll((B | (1ULL << RUN)) >> (m + 1));
    const bool ext_m = (vx_m == first && firstExt) || (vx_m == last && lastExt);

    phase1_mfma(s_pf[wslot], P, w1frag, j);

    // ext lanes: issue global seam-row loads now (covered by local loop below)
    float vf[16];
    if (ext_m) {
        const float* vr = v1 + (size_t)vx_m * 64 + q * 8;
        #pragma unroll
        for (int c = 0; c < 2; c++)
            #pragma unroll
            for (int i = 0; i < 8; i++) vf[c * 8 + i] = vr[c * 32 + i];
    }

    // A-frags: chunks 0,1 = pf1 rows (lane-distinct LDS reads)
    v8s ah[4], al[4];
    #pragma unroll
    for (int c = 0; c < 2; c++) {
        float f[8];
        #pragma unroll
        for (int i = 0; i < 8; i++) f[i] = s_pf[wslot][m][c * 32 + q * 8 + i];
        split8(f, ah[c], al[c]);
    }
    // interior lanes: v1 row = local segment max over own pf1 (identical set)
    if (!ext_m) {
        #pragma unroll
        for (int i = 0; i < 16; i++) vf[i] = 0.f;
        for (int p = s_seg; p < e_seg; p++) {
            const float* row = s_pf[wslot][p];
            float4 a0 = *(const float4*)&row[q * 8];
            float4 a1 = *(const float4*)&row[q * 8 + 4];
            float4 b0 = *(const float4*)&row[32 + q * 8];
            float4 b1 = *(const float4*)&row[32 + q * 8 + 4];
            vf[0] = fmaxf(vf[0], a0.x);  vf[1] = fmaxf(vf[1], a0.y);
            vf[2] = fmaxf(vf[2], a0.z);  vf[3] = fmaxf(vf[3], a0.w);
            vf[4] = fmaxf(vf[4], a1.x);  vf[5] = fmaxf(vf[5], a1.y);
            vf[6] = fmaxf(vf[6], a1.z);  vf[7] = fmaxf(vf[7], a1.w);
            vf[8] = fmaxf(vf[8], b0.x);  vf[9] = fmaxf(vf[9], b0.y);
            vf[10] = fmaxf(vf[10], b0.z); vf[11] = fmaxf(vf[11], b0.w);
            vf[12] = fmaxf(vf[12], b1.x); vf[13] = fmaxf(vf[13], b1.y);
            vf[14] = fmaxf(vf[14], b1.z); vf[15] = fmaxf(vf[15], b1.w);
        }
    }
    // chunks 2,3 = v1 row (segment-constant: rides inside the acc)
    split8(vf + 0, ah[2], al[2]);
    split8(vf + 8, ah[3], al[3]);
    __builtin_amdgcn_wave_barrier();   // A reads done before D overwrites s_pf

    #pragma unroll
    for (int t = 0; t < 4; t++) {
        v8s bh[4], bl[4];
        #pragma unroll
        for (int c = 0; c < 4; c++) {
            bh[c] = w2frag[((t * 4 + c) * 2 + 0) * 64 + j];
            bl[c] = w2frag[((t * 4 + c) * 2 + 1) * 64 + j];
        }
        v4f acc = {0.f, 0.f, 0.f, 0.f};
        #pragma unroll
        for (int c = 0; c < 4; c++) {
            acc = __builtin_amdgcn_mfma_f32_16x16x32_bf16(ah[c], bh[c], acc, 0, 0, 0);
            acc = __builtin_amdgcn_mfma_f32_16x16x32_bf16(al[c], bh[c], acc, 0, 0, 0);
            acc = __builtin_amdgcn_mfma_f32_16x16x32_bf16(ah[c], bl[c], acc, 0, 0, 0);
        }
        #pragma unroll
        for (int r = 0; r < 4; r++) s_pf[wslot][q * 4 + r][t * 16 + m] = acc[r];
    }
    __builtin_amdgcn_wave_barrier();

    int vprev = first;
    float smax = -3.4e38f;
    for (int p = 0; p < RUN; p++) {
        int vp = rli(P.vx, p);
        if (vp != vprev) {
            float r = fmaxf(smax, 0.f);
            size_t o = (size_t)vprev * 64 + j;
            bool ua = (vprev == first && firstExt) || (vprev == last && lastExt);
            if (ua) atomicMax((int*)out + o, __float_as_int(r));
            else out[o] = r;
            vprev = vp; smax = -3.4e38f;
        }
        smax = fmaxf(smax, s_pf[wslot][p][j]);
    }
    {
        float r = fmaxf(smax, 0.f);
        size_t o = (size_t)vprev * 64 + j;
        bool ua = (vprev == first && firstExt) || (vprev == last && lastExt);
        if (ua) atomicMax((int*)out + o, __float_as_int(r));
        else out[o] = r;
    }
}

extern "C" void kernel_launch(void* const* d_in, const int* in_sizes, int n_in,
                              void* d_out, int out_size, void* d_ws, size_t ws_size,
                              hipStream_t stream) {
    const float* pts = (const float*)d_in[0];
    const float* W1  = (const float*)d_in[1];
    const float* W2  = (const float*)d_in[2];
    float* out = (float*)d_out;

    float4* vmean4 = (float4*)d_ws;                         // CANVAS float4
    float*  v1     = (float*)(vmean4 + CANVASc);            // CANVAS*64
    float4* pos4   = (float4*)(v1 + (size_t)CANVASc * 64);  // NPTS float4
    float*  e1b    = (float*)(pos4 + NPTS);                 // NPTS
    int*    cellb  = (int*)(e1b + NPTS);                    // NPTS
    int*    rankb  = cellb + NPTS;                          // NPTS
    int*    cellu  = rankb + NPTS;                          // NPTS
    v8s*    w2frag = (v8s*)(cellu + NPTS);                  // 2048 v8s
    v8s*    w1frag = w2frag + 2048;                         // 512 v8s
    int*    cnt    = (int*)(w1frag + 512);                  // CANVAS
    int*    gcur   = cnt + CANVASc;                         // 1
    int*    scnt   = gcur + 1;                              // 1
    int*    slist  = scnt + 1;                              // NRUNS
    int*    cursor = slist + NRUNS;                         // CANVAS

    hipMemsetAsync(cnt, 0, (size_t)(CANVASc + 2) * 4, stream);   // cnt+gcur+scnt

    k_stats  <<<GPTS + 5, 256, 0, stream>>>(pts, cnt, rankb, cellu,
                                            W1, W2, w1frag, w2frag);
    k_alloc  <<<GVOX, 256, 0, stream>>>(cnt, cursor, gcur);
    k_scatter<<<GPTS, 256, 0, stream>>>(pts, cursor, rankb, cellu,
                                        pos4, e1b, cellb);
    kV       <<<GVOX + GSEAM, 256, 0, stream>>>(cnt, cursor, pos4, cellb,
                                                vmean4, (float4*)out, scnt, slist);
    kAL      <<<NRUNS / 4, 256, 0, stream>>>(scnt, slist, cnt, cursor, pos4, e1b,
                                             cellb, vmean4, W1, v1);
    kB       <<<NRUNS / 4, 256, 0, stream>>>(pos4, e1b, cellb, vmean4, w1frag,
                                             w2frag, v1, out);
}

// Round 12
// 222.768 us; speedup vs baseline: 1.1286x; 1.0146x over previous
//
#include <hip/hip_runtime.h>

#define NXc 468
#define NYc 468
#define CANVASc (468 * 468)   // 219024
#define NPTS 400000
#define RUN 16
#define NRUNS (NPTS / RUN)    // 25000 exactly
#define GPTS ((NPTS + 255) / 256)      // 1563
#define GVOX ((CANVASc + 255) / 256)   // 856
#define GSEAM ((NRUNS + 255) / 256)    // 98

#define PCMIN_X (-74.88f)
#define PCMIN_Y (-74.88f)
#define VOX_X 0.32f
#define VOX_Y 0.32f
#define OFF_X (-74.72f)
#define OFF_Y (-74.72f)
#define OFF_Z (1.0f)

typedef __attribute__((ext_vector_type(8))) short v8s;   // 8 bf16 (4 VGPRs)
typedef __attribute__((ext_vector_type(4))) float v4f;   // MFMA acc

static_assert(sizeof(__bf16) == 2, "bf16 must be 2 bytes");

__device__ __forceinline__ int rli(int x, int p) {
    return __builtin_amdgcn_readlane(x, p);
}
__device__ __forceinline__ float rlf(float x, int p) {
    return __int_as_float(__builtin_amdgcn_readlane(__float_as_int(x), p));
}

// Native bf16 split: hi = RNE(f), lo = RNE(f - hi).
// R3 A/B: cut kB VALUBusy 37->26% (vs manual bit-twiddle RNE). Keep.
__device__ __forceinline__ void split8(const float* f, v8s& h, v8s& l) {
    #pragma unroll
    for (int i = 0; i < 8; i += 2) {
        __bf16 h0 = (__bf16)f[i];
        __bf16 h1 = (__bf16)f[i + 1];
        h[i]     = __builtin_bit_cast(short, h0);
        h[i + 1] = __builtin_bit_cast(short, h1);
        float l0 = f[i]     - (float)h0;
        float l1 = f[i + 1] - (float)h1;
        l[i]     = __builtin_bit_cast(short, (__bf16)l0);
        l[i + 1] = __builtin_bit_cast(short, (__bf16)l1);
    }
}

// Bins MUST stay bit-identical everywhere (fp32 division, no reciprocal).
__device__ __forceinline__ int voxel_cell(float x, float y, int& cx, int& cy) {
    cx = (int)floorf((x - PCMIN_X) / VOX_X);
    cy = (int)floorf((y - PCMIN_Y) / VOX_Y);
    cx = min(max(cx, 0), NXc - 1);
    cy = min(max(cy, 0), NYc - 1);
    return cy * NXc + cx;
}

// kW body: bf16 hi/lo B-fragments for W2 (4 tiles x 4 K-chunks) and W1
// (4 tiles, K=32, rows >= 11 zero). B[k][n]: n=lane&15, k=c*32+(lane>>4)*8+i.
__device__ __forceinline__ void kw_body(int tid,
                                        const float* __restrict__ W1,
                                        const float* __restrict__ W2,
                                        v8s* __restrict__ w1frag,
                                        v8s* __restrict__ w2frag) {
    if (tid < 1024) {
        int f = tid >> 6, lane = tid & 63;
        int t = f >> 2, c = f & 3;
        int q = lane >> 4, n = lane & 15;
        float v[8];
        #pragma unroll
        for (int i = 0; i < 8; i++) v[i] = W2[(c * 32 + q * 8 + i) * 64 + t * 16 + n];
        v8s h, l;
        split8(v, h, l);
        w2frag[(f * 2 + 0) * 64 + lane] = h;
        w2frag[(f * 2 + 1) * 64 + lane] = l;
    } else if (tid < 1280) {
        int f = (tid - 1024) >> 6, lane = (tid - 1024) & 63;
        int q = lane >> 4, n = lane & 15;
        float v[8];
        #pragma unroll
        for (int i = 0; i < 8; i++) {
            int k = q * 8 + i;
            v[i] = (k < 11) ? W1[k * 64 + f * 16 + n] : 0.f;
        }
        v8s h, l;
        split8(v, h, l);
        w1frag[(f * 2 + 0) * 64 + lane] = h;
        w1frag[(f * 2 + 1) * 64 + lane] = l;
    }
}

// Pass 0 (R10): counts + per-point RANK (the atomic's return value — free)
// + packed cell. Rank makes k_scatter atomic-free: pos = cursor[fl]+rank.
// Tail blocks build W-fragments (dispatch merge).
__global__ __launch_bounds__(256) void k_stats(const float* __restrict__ pts,
                                               int* __restrict__ cnt,
                                               int* __restrict__ rankb,
                                               int* __restrict__ cellu,
                                               const float* __restrict__ W1,
                                               const float* __restrict__ W2,
                                               v8s* __restrict__ w1frag,
                                               v8s* __restrict__ w2frag) {
    int b = blockIdx.x;
    if (b >= GPTS) {
        kw_body((b - GPTS) * 256 + threadIdx.x, W1, W2, w1frag, w2frag);
        return;
    }
    int i = b * 256 + threadIdx.x;
    if (i >= NPTS) return;
    float x = pts[i * 5 + 0], y = pts[i * 5 + 1];
    int cx, cy;
    int fl = voxel_cell(x, y, cx, cy);
    rankb[i] = atomicAdd(&cnt[fl], 1);
    cellu[i] = cx | (cy << 16);
}

// Pass 1: exclusive-scan alloc -> cursor (= segment start, never bumped)
__global__ __launch_bounds__(256) void k_alloc(const int* __restrict__ cnt,
                                               int* __restrict__ cursor,
                                               int* __restrict__ gcur) {
    int v = blockIdx.x * 256 + threadIdx.x;
    int lane = threadIdx.x & 63;
    int c = (v < CANVASc) ? cnt[v] : 0;
    int scan = c;
    #pragma unroll
    for (int off = 1; off < 64; off <<= 1) {
        int t = __shfl_up(scan, off, 64);
        if (lane >= off) scan += t;
    }
    int total = __shfl(scan, 63, 64);
    int base = 0;
    if (lane == 0 && total > 0) base = atomicAdd(gcur, total);
    base = __shfl(base, 0, 64);
    if (v < CANVASc) cursor[v] = base + scan - c;
}

// gather one point record (coalesced-ish 20B strided read)
__device__ __forceinline__ void gather_pt(const float* __restrict__ pts, int pi,
                                          float4& A, float& e1) {
    const float* pp = pts + (size_t)pi * 5;
    __builtin_memcpy(&A, pp, 16);   // 4B-aligned dwordx4
    e1 = pp[4];
}

// Pass 2 (R10): ATOMIC-FREE record scatter. pos = cursor[fl] + rank[i].
__global__ __launch_bounds__(256) void k_scatter(const float* __restrict__ pts,
                                                 const int* __restrict__ cursor,
                                                 const int* __restrict__ rankb,
                                                 const int* __restrict__ cellu,
                                                 float4* __restrict__ pos4,
                                                 float* __restrict__ e1b,
                                                 int* __restrict__ cellb) {
    int i = blockIdx.x * 256 + threadIdx.x;
    if (i >= NPTS) return;
    float4 A; float e1;
    gather_pt(pts, i, A, e1);
    int cell = cellu[i];
    int cx = cell & 0xFFFF, cy = cell >> 16;
    int fl = cy * NXc + cx;
    int pos = cursor[fl] + rankb[i];
    pos4[pos] = A;
    e1b[pos] = e1;
    cellb[pos] = cell;
}

// kV: per-voxel vmean + empty-row out-zeroing; tail blocks zero the OUT
// rows of seam voxels (per-boundary; a 2-boundary voxel is zeroed twice —
// benign). R11: no slist/scnt — kAL detects seams inline.
__global__ __launch_bounds__(256) void kV(const int* __restrict__ cnt,
                                          const int* __restrict__ cursor,
                                          const float4* __restrict__ pos4,
                                          const int* __restrict__ cellb,
                                          float4* __restrict__ vmean4,
                                          float4* __restrict__ out4) {
    int b = blockIdx.x;
    if (b >= GVOX) {
        int w = (b - GVOX) * 256 + threadIdx.x;   // boundary index
        if (w == 0 || w >= NRUNS) return;
        int bb = w * RUN;
        int ca = cellb[bb - 1], cb = cellb[bb];
        if (ca != cb) return;                     // no voxel spans this boundary
        int cx = ca & 0xFFFF, cy = ca >> 16;
        int va = cy * NXc + cx;
        float4 z = make_float4(0.f, 0.f, 0.f, 0.f);
        float4* o = out4 + (size_t)va * 16;
        #pragma unroll
        for (int i = 0; i < 16; i++) o[i] = z;
        return;
    }
    int v = b * 256 + threadIdx.x;
    if (v >= CANVASc) return;
    int c = cnt[v];
    if (c == 0) {
        float4 z = make_float4(0.f, 0.f, 0.f, 0.f);
        float4* o = out4 + (size_t)v * 16;
        #pragma unroll
        for (int i = 0; i < 16; i++) o[i] = z;
        return;
    }
    int start = cursor[v];              // exclusive-scan base = segment start
    float sx = 0.f, sy = 0.f, sz = 0.f;
    for (int i = 0; i < c; i++) {
        float4 p = pos4[start + i];
        sx += p.x; sy += p.y; sz += p.z;
    }
    float inv = 1.0f / (float)c;
    vmean4[v] = make_float4(sx * inv, sy * inv, sz * inv, 0.f);
}

// kAL (R11): BOUNDARY-indexed seam v1. One wave per wave-boundary w;
// inline seam detect (same predicate as kB's firstExt); computes the
// full-voxel segment max (so any seam row of a voxel holds the complete
// max), stores v1c[w*64+j]. v1c is 6.4 MB (was 56 MB canvas-indexed) —
// L2-resident, no voxel->slot map needed, no zero-init, no atomics.
__global__ __launch_bounds__(256) void kAL(const int* __restrict__ cnt,
                                           const int* __restrict__ cursor,
                                           const float4* __restrict__ pos4,
                                           const float* __restrict__ e1b,
                                           const int* __restrict__ cellb,
                                           const float4* __restrict__ vmean4,
                                           const float* __restrict__ W1,
                                           float* __restrict__ v1c) {
    int j = threadIdx.x & 63;
    int wslot = threadIdx.x >> 6;
    int w = blockIdx.x * 4 + wslot;          // boundary id
    if (w == 0 || w >= NRUNS) return;
    int bb = w * RUN;
    int ca = cellb[bb - 1], cb = cellb[bb];
    if (ca != cb) return;                    // not a seam
    int cx = ca & 0xFFFF, cy = ca >> 16;
    int v = cy * NXc + cx;
    float wgt[11];
    #pragma unroll
    for (int k = 0; k < 11; k++) wgt[k] = W1[k * 64 + j];
    int c = cnt[v];
    int start = cursor[v];
    float vmax = 0.f;                        // relu floor
    for (int pb = 0; pb < c; pb += 64) {
        int pc = min(c - pb, 64);
        float f[11];
        #pragma unroll
        for (int k = 0; k < 11; k++) f[k] = 0.f;
        if (j < pc) {
            int idx = start + pb + j;
            float4 A = pos4[idx];
            float e1 = e1b[idx];
            int cell = cellb[idx];
            int ccx = cell & 0xFFFF, ccy = cell >> 16;
            float4 mv = vmean4[v];
            f[0] = A.x; f[1] = A.y; f[2] = A.z; f[3] = A.w; f[4] = e1;
            f[5] = A.x - mv.x; f[6] = A.y - mv.y; f[7] = A.z - mv.z;
            f[8] = A.x - (ccx * VOX_X + OFF_X);
            f[9] = A.y - (ccy * VOX_Y + OFF_Y);
            f[10] = A.z - OFF_Z;
        }
        for (int p = 0; p < pc; p++) {
            float acc = 0.f;
            #pragma unroll
            for (int k = 0; k < 11; k++)
                acc = fmaf(rlf(f[k], p), wgt[k], acc);
            vmax = fmaxf(vmax, acc);
        }
    }
    v1c[(size_t)w * 64 + j] = vmax;
}

// Per-lane prep: lanes 0..15 read their sorted record (coalesced float4)
// + packed cell + vmean; lanes 16/17 peek neighbor cells for edge detection.
struct PtRegs {
    float4 A;
    float  e1, fcx, fcy, fcz;
    float  mx, my, mz;
    int    vx;
};
__device__ __forceinline__ PtRegs load_pt(const float4* __restrict__ pos4,
                                          const float* __restrict__ e1b,
                                          const int* __restrict__ cellb,
                                          const float4* __restrict__ vmean4,
                                          int base, int j) {
    PtRegs r;
    r.A = make_float4(0.f, 0.f, 0.f, 0.f);
    r.e1 = r.fcx = r.fcy = r.fcz = r.mx = r.my = r.mz = 0.f;
    r.vx = -1;
    int idx = -1;
    if (j < RUN) idx = base + j;
    else if (j == 16) idx = (base + RUN < NPTS) ? base + RUN : -1;
    else if (j == 17) idx = base - 1;
    if (idx >= 0) {
        int cell = cellb[idx];
        int cx = cell & 0xFFFF, cy = cell >> 16;
        int vv = cy * NXc + cx;
        r.vx = vv;
        if (j < RUN) {
            float4 A = pos4[idx];
            r.A = A;
            r.e1 = e1b[idx];
            r.fcx = A.x - (cx * VOX_X + OFF_X);
            r.fcy = A.y - (cy * VOX_Y + OFF_Y);
            r.fcz = A.z - OFF_Z;
            float4 m = vmean4[vv];
            r.mx = m.x; r.my = m.y; r.mz = m.z;
        }
    }
    return r;
}

#define PSTR 68   // LDS row stride (floats); 68 -> 2-way bank alias (free)

// Shared phase-1: features -> LDS rows -> MFMA (K=32, 12 mfma) -> relu(D) -> LDS.
// On return s_pf rows 0..15 hold relu'd pf1[p][0..63].
__device__ __forceinline__ void phase1_mfma(float (*s_pf)[PSTR], const PtRegs& P,
                                            const v8s* __restrict__ w1frag, int j) {
    if (j < RUN) {
        float* row = s_pf[j];
        row[0] = P.A.x; row[1] = P.A.y; row[2] = P.A.z; row[3] = P.A.w; row[4] = P.e1;
        row[5] = P.A.x - P.mx; row[6] = P.A.y - P.my; row[7] = P.A.z - P.mz;
        row[8] = P.fcx; row[9] = P.fcy; row[10] = P.fcz;
        #pragma unroll
        for (int t = 11; t < 16; t++) row[t] = 0.f;
    }
    __builtin_amdgcn_wave_barrier();

    const int m = j & 15, q = j >> 4;
    v8s fh = {0,0,0,0,0,0,0,0}, fl_ = {0,0,0,0,0,0,0,0};
    if (q < 2) {
        float f8[8];
        #pragma unroll
        for (int i = 0; i < 8; i++) f8[i] = s_pf[m][q * 8 + i];
        split8(f8, fh, fl_);
    }
    v4f d[4];
    #pragma unroll
    for (int t = 0; t < 4; t++) {
        v8s bh = w1frag[(t * 2 + 0) * 64 + j];
        v8s bl = w1frag[(t * 2 + 1) * 64 + j];
        v4f acc = {0.f, 0.f, 0.f, 0.f};
        acc = __builtin_amdgcn_mfma_f32_16x16x32_bf16(fh,  bh, acc, 0, 0, 0);
        acc = __builtin_amdgcn_mfma_f32_16x16x32_bf16(fl_, bh, acc, 0, 0, 0);
        acc = __builtin_amdgcn_mfma_f32_16x16x32_bf16(fh,  bl, acc, 0, 0, 0);
        d[t] = acc;
    }
    __builtin_amdgcn_wave_barrier();   // feature reads complete before overwrite
    #pragma unroll
    for (int t = 0; t < 4; t++)
        #pragma unroll
        for (int r = 0; r < 4; r++)
            s_pf[q * 4 + r][t * 16 + m] = fmaxf(d[t][r], 0.f);
    __builtin_amdgcn_wave_barrier();
}

// kB: D[p][j] = [pf1[p], v1[vox(p)]] @ W2 via MFMA -> segment max -> out.
// R6: interior lanes rebuild v1 locally; ext lanes read the BOUNDARY-indexed
// seam row (R11): bidx = first-ext ? wave : wave+1 — no voxel map needed.
__global__ __launch_bounds__(256) void kB(const float4* __restrict__ pos4,
                                          const float* __restrict__ e1b,
                                          const int* __restrict__ cellb,
                                          const float4* __restrict__ vmean4,
                                          const v8s* __restrict__ w1frag,
                                          const v8s* __restrict__ w2frag,
                                          const float* __restrict__ v1c,
                                          float* __restrict__ out) {
    __shared__ float s_pf[4][RUN][PSTR];
    int wslot = threadIdx.x >> 6;
    int wave = blockIdx.x * 4 + wslot;
    int j = threadIdx.x & 63;
    int base = wave * RUN;

    PtRegs P = load_pt(pos4, e1b, cellb, vmean4, base, j);

    const int m = j & 15, q = j >> 4;

    const int first = rli(P.vx, 0), last = rli(P.vx, RUN - 1);
    const bool firstExt = (rli(P.vx, 17) == first);
    const bool lastExt  = (rli(P.vx, 16) == last);

    // Per-lane segment bounds for point m (ballot over run boundaries).
    int vx_m = __builtin_amdgcn_ds_bpermute(m << 2, P.vx);
    int vx_prev = __shfl_up(P.vx, 1, 64);
    unsigned long long B =
        __ballot((j < RUN) && ((j == 0) || (P.vx != vx_prev)));
    int s_seg = 63 - __builtin_clzll(B & ((2ULL << m) - 1ULL));
    int e_seg = m + 1 + (int)__builtin_ctzll((B | (1ULL << RUN)) >> (m + 1));
    const bool fext_m = (vx_m == first && firstExt);
    const bool ext_m = fext_m || (vx_m == last && lastExt);
    const int bidx = fext_m ? wave : (wave + 1);   // seam row for this lane

    phase1_mfma(s_pf[wslot], P, w1frag, j);

    // ext lanes: issue seam-row loads now (covered by local loop below)
    float vf[16];
    if (ext_m) {
        const float* vr = v1c + (size_t)bidx * 64 + q * 8;
        #pragma unroll
        for (int c = 0; c < 2; c++)
            #pragma unroll
            for (int i = 0; i < 8; i++) vf[c * 8 + i] = vr[c * 32 + i];
    }

    // A-frags: chunks 0,1 = pf1 rows (lane-distinct LDS reads)
    v8s ah[4], al[4];
    #pragma unroll
    for (int c = 0; c < 2; c++) {
        float f[8];
        #pragma unroll
        for (int i = 0; i < 8; i++) f[i] = s_pf[wslot][m][c * 32 + q * 8 + i];
        split8(f, ah[c], al[c]);
    }
    // interior lanes: v1 row = local segment max over own pf1 (identical set)
    if (!ext_m) {
        #pragma unroll
        for (int i = 0; i < 16; i++) vf[i] = 0.f;
        for (int p = s_seg; p < e_seg; p++) {
            const float* row = s_pf[wslot][p];
            float4 a0 = *(const float4*)&row[q * 8];
            float4 a1 = *(const float4*)&row[q * 8 + 4];
            float4 b0 = *(const float4*)&row[32 + q * 8];
            float4 b1 = *(const float4*)&row[32 + q * 8 + 4];
            vf[0] = fmaxf(vf[0], a0.x);  vf[1] = fmaxf(vf[1], a0.y);
            vf[2] = fmaxf(vf[2], a0.z);  vf[3] = fmaxf(vf[3], a0.w);
            vf[4] = fmaxf(vf[4], a1.x);  vf[5] = fmaxf(vf[5], a1.y);
            vf[6] = fmaxf(vf[6], a1.z);  vf[7] = fmaxf(vf[7], a1.w);
            vf[8] = fmaxf(vf[8], b0.x);  vf[9] = fmaxf(vf[9], b0.y);
            vf[10] = fmaxf(vf[10], b0.z); vf[11] = fmaxf(vf[11], b0.w);
            vf[12] = fmaxf(vf[12], b1.x); vf[13] = fmaxf(vf[13], b1.y);
            vf[14] = fmaxf(vf[14], b1.z); vf[15] = fmaxf(vf[15], b1.w);
        }
    }
    // chunks 2,3 = v1 row (segment-constant: rides inside the acc)
    split8(vf + 0, ah[2], al[2]);
    split8(vf + 8, ah[3], al[3]);
    __builtin_amdgcn_wave_barrier();   // A reads done before D overwrites s_pf

    #pragma unroll
    for (int t = 0; t < 4; t++) {
        v8s bh[4], bl[4];
        #pragma unroll
        for (int c = 0; c < 4; c++) {
            bh[c] = w2frag[((t * 4 + c) * 2 + 0) * 64 + j];
            bl[c] = w2frag[((t * 4 + c) * 2 + 1) * 64 + j];
        }
        v4f acc = {0.f, 0.f, 0.f, 0.f};
        #pragma unroll
        for (int c = 0; c < 4; c++) {
            acc = __builtin_amdgcn_mfma_f32_16x16x32_bf16(ah[c], bh[c], acc, 0, 0, 0);
            acc = __builtin_amdgcn_mfma_f32_16x16x32_bf16(al[c], bh[c], acc, 0, 0, 0);
            acc = __builtin_amdgcn_mfma_f32_16x16x32_bf16(ah[c], bl[c], acc, 0, 0, 0);
        }
        #pragma unroll
        for (int r = 0; r < 4; r++) s_pf[wslot][q * 4 + r][t * 16 + m] = acc[r];
    }
    __builtin_amdgcn_wave_barrier();

    int vprev = first;
    float smax = -3.4e38f;
    for (int p = 0; p < RUN; p++) {
        int vp = rli(P.vx, p);
        if (vp != vprev) {
            float r = fmaxf(smax, 0.f);
            size_t o = (size_t)vprev * 64 + j;
            bool ua = (vprev == first && firstExt) || (vprev == last && lastExt);
            if (ua) atomicMax((int*)out + o, __float_as_int(r));
            else out[o] = r;
            vprev = vp; smax = -3.4e38f;
        }
        smax = fmaxf(smax, s_pf[wslot][p][j]);
    }
    {
        float r = fmaxf(smax, 0.f);
        size_t o = (size_t)vprev * 64 + j;
        bool ua = (vprev == first && firstExt) || (vprev == last && lastExt);
        if (ua) atomicMax((int*)out + o, __float_as_int(r));
        else out[o] = r;
    }
}

extern "C" void kernel_launch(void* const* d_in, const int* in_sizes, int n_in,
                              void* d_out, int out_size, void* d_ws, size_t ws_size,
                              hipStream_t stream) {
    const float* pts = (const float*)d_in[0];
    const float* W1  = (const float*)d_in[1];
    const float* W2  = (const float*)d_in[2];
    float* out = (float*)d_out;

    float4* vmean4 = (float4*)d_ws;                         // CANVAS float4
    float*  v1c    = (float*)(vmean4 + CANVASc);            // NRUNS*64 (6.4 MB)
    float4* pos4   = (float4*)(v1c + (size_t)NRUNS * 64);   // NPTS float4
    float*  e1b    = (float*)(pos4 + NPTS);                 // NPTS
    int*    cellb  = (int*)(e1b + NPTS);                    // NPTS
    int*    rankb  = cellb + NPTS;                          // NPTS
    int*    cellu  = rankb + NPTS;                          // NPTS
    v8s*    w2frag = (v8s*)(cellu + NPTS);                  // 2048 v8s
    v8s*    w1frag = w2frag + 2048;                         // 512 v8s
    int*    cnt    = (int*)(w1frag + 512);                  // CANVAS
    int*    gcur   = cnt + CANVASc;                         // 1
    int*    cursor = gcur + 1;                              // CANVAS

    hipMemsetAsync(cnt, 0, (size_t)(CANVASc + 1) * 4, stream);   // cnt + gcur

    k_stats  <<<GPTS + 5, 256, 0, stream>>>(pts, cnt, rankb, cellu,
                                            W1, W2, w1frag, w2frag);
    k_alloc  <<<GVOX, 256, 0, stream>>>(cnt, cursor, gcur);
    k_scatter<<<GPTS, 256, 0, stream>>>(pts, cursor, rankb, cellu,
                                        pos4, e1b, cellb);
    kV       <<<GVOX + GSEAM, 256, 0, stream>>>(cnt, cursor, pos4, cellb,
                                                vmean4, (float4*)out);
    kAL      <<<NRUNS / 4, 256, 0, stream>>>(cnt, cursor, pos4, e1b,
                                             cellb, vmean4, W1, v1c);
    kB       <<<NRUNS / 4, 256, 0, stream>>>(pos4, e1b, cellb, vmean4, w1frag,
                                             w2frag, v1c, out);
}

// Round 13
// 221.846 us; speedup vs baseline: 1.1333x; 1.0042x over previous
//
#include <hip/hip_runtime.h>

#define NXc 468
#define NYc 468
#define CANVASc (468 * 468)   // 219024
#define NPTS 400000
#define RUN 16
#define NRUNS (NPTS / RUN)    // 25000 exactly
#define GPTS ((NPTS + 255) / 256)      // 1563
#define GVOX ((CANVASc + 255) / 256)   // 856
#define GBND (NRUNS / 4)               // 6250 (wave-per-boundary tail)

#define PCMIN_X (-74.88f)
#define PCMIN_Y (-74.88f)
#define VOX_X 0.32f
#define VOX_Y 0.32f
#define OFF_X (-74.72f)
#define OFF_Y (-74.72f)
#define OFF_Z (1.0f)

typedef __attribute__((ext_vector_type(8))) short v8s;   // 8 bf16 (4 VGPRs)
typedef __attribute__((ext_vector_type(4))) float v4f;   // MFMA acc

static_assert(sizeof(__bf16) == 2, "bf16 must be 2 bytes");

__device__ __forceinline__ int rli(int x, int p) {
    return __builtin_amdgcn_readlane(x, p);
}
__device__ __forceinline__ float rlf(float x, int p) {
    return __int_as_float(__builtin_amdgcn_readlane(__float_as_int(x), p));
}

// Native bf16 split: hi = RNE(f), lo = RNE(f - hi).
// R3 A/B: cut kB VALUBusy 37->26% (vs manual bit-twiddle RNE). Keep.
__device__ __forceinline__ void split8(const float* f, v8s& h, v8s& l) {
    #pragma unroll
    for (int i = 0; i < 8; i += 2) {
        __bf16 h0 = (__bf16)f[i];
        __bf16 h1 = (__bf16)f[i + 1];
        h[i]     = __builtin_bit_cast(short, h0);
        h[i + 1] = __builtin_bit_cast(short, h1);
        float l0 = f[i]     - (float)h0;
        float l1 = f[i + 1] - (float)h1;
        l[i]     = __builtin_bit_cast(short, (__bf16)l0);
        l[i + 1] = __builtin_bit_cast(short, (__bf16)l1);
    }
}

// Bins MUST stay bit-identical everywhere (fp32 division, no reciprocal).
__device__ __forceinline__ int voxel_cell(float x, float y, int& cx, int& cy) {
    cx = (int)floorf((x - PCMIN_X) / VOX_X);
    cy = (int)floorf((y - PCMIN_Y) / VOX_Y);
    cx = min(max(cx, 0), NXc - 1);
    cy = min(max(cy, 0), NYc - 1);
    return cy * NXc + cx;
}

// kW body: bf16 hi/lo B-fragments for W2 (4 tiles x 4 K-chunks) and W1
// (4 tiles, K=32, rows >= 11 zero). B[k][n]: n=lane&15, k=c*32+(lane>>4)*8+i.
__device__ __forceinline__ void kw_body(int tid,
                                        const float* __restrict__ W1,
                                        const float* __restrict__ W2,
                                        v8s* __restrict__ w1frag,
                                        v8s* __restrict__ w2frag) {
    if (tid < 1024) {
        int f = tid >> 6, lane = tid & 63;
        int t = f >> 2, c = f & 3;
        int q = lane >> 4, n = lane & 15;
        float v[8];
        #pragma unroll
        for (int i = 0; i < 8; i++) v[i] = W2[(c * 32 + q * 8 + i) * 64 + t * 16 + n];
        v8s h, l;
        split8(v, h, l);
        w2frag[(f * 2 + 0) * 64 + lane] = h;
        w2frag[(f * 2 + 1) * 64 + lane] = l;
    } else if (tid < 1280) {
        int f = (tid - 1024) >> 6, lane = (tid - 1024) & 63;
        int q = lane >> 4, n = lane & 15;
        float v[8];
        #pragma unroll
        for (int i = 0; i < 8; i++) {
            int k = q * 8 + i;
            v[i] = (k < 11) ? W1[k * 64 + f * 16 + n] : 0.f;
        }
        v8s h, l;
        split8(v, h, l);
        w1frag[(f * 2 + 0) * 64 + lane] = h;
        w1frag[(f * 2 + 1) * 64 + lane] = l;
    }
}

// Pass 0 (R10): counts + per-point RANK (the atomic's return value — free)
// + packed cell. Rank makes k_scatter atomic-free: pos = cursor[fl]+rank.
// Tail blocks build W-fragments (dispatch merge).
__global__ __launch_bounds__(256) void k_stats(const float* __restrict__ pts,
                                               int* __restrict__ cnt,
                                               int* __restrict__ rankb,
                                               int* __restrict__ cellu,
                                               const float* __restrict__ W1,
                                               const float* __restrict__ W2,
                                               v8s* __restrict__ w1frag,
                                               v8s* __restrict__ w2frag) {
    int b = blockIdx.x;
    if (b >= GPTS) {
        kw_body((b - GPTS) * 256 + threadIdx.x, W1, W2, w1frag, w2frag);
        return;
    }
    int i = b * 256 + threadIdx.x;
    if (i >= NPTS) return;
    float x = pts[i * 5 + 0], y = pts[i * 5 + 1];
    int cx, cy;
    int fl = voxel_cell(x, y, cx, cy);
    rankb[i] = atomicAdd(&cnt[fl], 1);
    cellu[i] = cx | (cy << 16);
}

// Pass 1: exclusive-scan alloc -> cursor (= segment start, never bumped)
__global__ __launch_bounds__(256) void k_alloc(const int* __restrict__ cnt,
                                               int* __restrict__ cursor,
                                               int* __restrict__ gcur) {
    int v = blockIdx.x * 256 + threadIdx.x;
    int lane = threadIdx.x & 63;
    int c = (v < CANVASc) ? cnt[v] : 0;
    int scan = c;
    #pragma unroll
    for (int off = 1; off < 64; off <<= 1) {
        int t = __shfl_up(scan, off, 64);
        if (lane >= off) scan += t;
    }
    int total = __shfl(scan, 63, 64);
    int base = 0;
    if (lane == 0 && total > 0) base = atomicAdd(gcur, total);
    base = __shfl(base, 0, 64);
    if (v < CANVASc) cursor[v] = base + scan - c;
}

// gather one point record (coalesced-ish 20B strided read)
__device__ __forceinline__ void gather_pt(const float* __restrict__ pts, int pi,
                                          float4& A, float& e1) {
    const float* pp = pts + (size_t)pi * 5;
    __builtin_memcpy(&A, pp, 16);   // 4B-aligned dwordx4
    e1 = pp[4];
}

// Pass 2 (R10): ATOMIC-FREE record scatter. pos = cursor[fl] + rank[i].
__global__ __launch_bounds__(256) void k_scatter(const float* __restrict__ pts,
                                                 const int* __restrict__ cursor,
                                                 const int* __restrict__ rankb,
                                                 const int* __restrict__ cellu,
                                                 float4* __restrict__ pos4,
                                                 float* __restrict__ e1b,
                                                 int* __restrict__ cellb) {
    int i = blockIdx.x * 256 + threadIdx.x;
    if (i >= NPTS) return;
    float4 A; float e1;
    gather_pt(pts, i, A, e1);
    int cell = cellu[i];
    int cx = cell & 0xFFFF, cy = cell >> 16;
    int fl = cy * NXc + cx;
    int pos = cursor[fl] + rankb[i];
    pos4[pos] = A;
    e1b[pos] = e1;
    cellb[pos] = cell;
}

// kV (R13): three roles in one dispatch.
//  - blocks [0, GVOX): per-voxel vmean + empty-voxel out-row zeroing.
//  - blocks [GVOX, GVOX+GBND): one WAVE per wave-boundary — if a voxel
//    spans it (seam), zero the out row AND compute the seam v1 row
//    (formerly kAL, merged here: its only kV dependency was vmean, now
//    computed inline via wave shuffle-reduce; ulp-level order difference
//    vs the sequential mean is ~1e-7, invisible next to bf16 rounding).
__global__ __launch_bounds__(256) void kV(const int* __restrict__ cnt,
                                          const int* __restrict__ cursor,
                                          const float4* __restrict__ pos4,
                                          const float* __restrict__ e1b,
                                          const int* __restrict__ cellb,
                                          const float* __restrict__ W1,
                                          float4* __restrict__ vmean4,
                                          float* __restrict__ v1c,
                                          float* __restrict__ out) {
    int b = blockIdx.x;
    if (b >= GVOX) {
        int j = threadIdx.x & 63;
        int wslot = threadIdx.x >> 6;
        int w = (b - GVOX) * 4 + wslot;       // boundary id
        if (w == 0 || w >= NRUNS) return;
        int bb = w * RUN;
        int ca = cellb[bb - 1], cb0 = cellb[bb];
        if (ca != cb0) return;                // no voxel spans this boundary
        int cx = ca & 0xFFFF, cy = ca >> 16;
        int v = cy * NXc + cx;
        int c = cnt[v];
        int start = cursor[v];
        out[(size_t)v * 64 + j] = 0.f;        // row only ever sees atomicMax

        // pass 1: voxel mean via wave shuffle-reduce
        float sx = 0.f, sy = 0.f, sz = 0.f;
        for (int pb = 0; pb < c; pb += 64) {
            int pc = min(c - pb, 64);
            if (j < pc) {
                float4 A = pos4[start + pb + j];
                sx += A.x; sy += A.y; sz += A.z;
            }
        }
        #pragma unroll
        for (int off = 1; off < 64; off <<= 1) {
            sx += __shfl_xor(sx, off, 64);
            sy += __shfl_xor(sy, off, 64);
            sz += __shfl_xor(sz, off, 64);
        }
        float inv = 1.0f / (float)c;
        float mx = sx * inv, my = sy * inv, mz = sz * inv;

        // pass 2: K=11 dot (lane j = W1 column j), segment max (relu floor)
        float wgt[11];
        #pragma unroll
        for (int k = 0; k < 11; k++) wgt[k] = W1[k * 64 + j];
        float vmax = 0.f;
        for (int pb = 0; pb < c; pb += 64) {
            int pc = min(c - pb, 64);
            float f[11];
            #pragma unroll
            for (int k = 0; k < 11; k++) f[k] = 0.f;
            if (j < pc) {
                int idx = start + pb + j;
                float4 A = pos4[idx];
                float e1 = e1b[idx];
                int cell = cellb[idx];
                int ccx = cell & 0xFFFF, ccy = cell >> 16;
                f[0] = A.x; f[1] = A.y; f[2] = A.z; f[3] = A.w; f[4] = e1;
                f[5] = A.x - mx; f[6] = A.y - my; f[7] = A.z - mz;
                f[8] = A.x - (ccx * VOX_X + OFF_X);
                f[9] = A.y - (ccy * VOX_Y + OFF_Y);
                f[10] = A.z - OFF_Z;
            }
            for (int p = 0; p < pc; p++) {
                float acc = 0.f;
                #pragma unroll
                for (int k = 0; k < 11; k++)
                    acc = fmaf(rlf(f[k], p), wgt[k], acc);
                vmax = fmaxf(vmax, acc);
            }
        }
        v1c[(size_t)w * 64 + j] = vmax;
        return;
    }
    int v = b * 256 + threadIdx.x;
    if (v >= CANVASc) return;
    int c = cnt[v];
    if (c == 0) {
        float4 z = make_float4(0.f, 0.f, 0.f, 0.f);
        float4* o = (float4*)out + (size_t)v * 16;
        #pragma unroll
        for (int i = 0; i < 16; i++) o[i] = z;
        return;
    }
    int start = cursor[v];              // exclusive-scan base = segment start
    float sx = 0.f, sy = 0.f, sz = 0.f;
    for (int i = 0; i < c; i++) {
        float4 p = pos4[start + i];
        sx += p.x; sy += p.y; sz += p.z;
    }
    float inv = 1.0f / (float)c;
    vmean4[v] = make_float4(sx * inv, sy * inv, sz * inv, 0.f);
}

// Per-lane prep: lanes 0..15 read their sorted record (coalesced float4)
// + packed cell + vmean; lanes 16/17 peek neighbor cells for edge detection.
struct PtRegs {
    float4 A;
    float  e1, fcx, fcy, fcz;
    float  mx, my, mz;
    int    vx;
};
__device__ __forceinline__ PtRegs load_pt(const float4* __restrict__ pos4,
                                          const float* __restrict__ e1b,
                                          const int* __restrict__ cellb,
                                          const float4* __restrict__ vmean4,
                                          int base, int j) {
    PtRegs r;
    r.A = make_float4(0.f, 0.f, 0.f, 0.f);
    r.e1 = r.fcx = r.fcy = r.fcz = r.mx = r.my = r.mz = 0.f;
    r.vx = -1;
    int idx = -1;
    if (j < RUN) idx = base + j;
    else if (j == 16) idx = (base + RUN < NPTS) ? base + RUN : -1;
    else if (j == 17) idx = base - 1;
    if (idx >= 0) {
        int cell = cellb[idx];
        int cx = cell & 0xFFFF, cy = cell >> 16;
        int vv = cy * NXc + cx;
        r.vx = vv;
        if (j < RUN) {
            float4 A = pos4[idx];
            r.A = A;
            r.e1 = e1b[idx];
            r.fcx = A.x - (cx * VOX_X + OFF_X);
            r.fcy = A.y - (cy * VOX_Y + OFF_Y);
            r.fcz = A.z - OFF_Z;
            float4 m = vmean4[vv];
            r.mx = m.x; r.my = m.y; r.mz = m.z;
        }
    }
    return r;
}

#define PSTR 68   // LDS row stride (floats); 68 -> 2-way bank alias (free)

// Shared phase-1: features -> LDS rows -> MFMA (K=32, 12 mfma) -> relu(D) -> LDS.
// On return s_pf rows 0..15 hold relu'd pf1[p][0..63].
__device__ __forceinline__ void phase1_mfma(float (*s_pf)[PSTR], const PtRegs& P,
                                            const v8s* __restrict__ w1frag, int j) {
    if (j < RUN) {
        float* row = s_pf[j];
        row[0] = P.A.x; row[1] = P.A.y; row[2] = P.A.z; row[3] = P.A.w; row[4] = P.e1;
        row[5] = P.A.x - P.mx; row[6] = P.A.y - P.my; row[7] = P.A.z - P.mz;
        row[8] = P.fcx; row[9] = P.fcy; row[10] = P.fcz;
        #pragma unroll
        for (int t = 11; t < 16; t++) row[t] = 0.f;
    }
    __builtin_amdgcn_wave_barrier();

    const int m = j & 15, q = j >> 4;
    v8s fh = {0,0,0,0,0,0,0,0}, fl_ = {0,0,0,0,0,0,0,0};
    if (q < 2) {
        float f8[8];
        #pragma unroll
        for (int i = 0; i < 8; i++) f8[i] = s_pf[m][q * 8 + i];
        split8(f8, fh, fl_);
    }
    v4f d[4];
    #pragma unroll
    for (int t = 0; t < 4; t++) {
        v8s bh = w1frag[(t * 2 + 0) * 64 + j];
        v8s bl = w1frag[(t * 2 + 1) * 64 + j];
        v4f acc = {0.f, 0.f, 0.f, 0.f};
        acc = __builtin_amdgcn_mfma_f32_16x16x32_bf16(fh,  bh, acc, 0, 0, 0);
        acc = __builtin_amdgcn_mfma_f32_16x16x32_bf16(fl_, bh, acc, 0, 0, 0);
        acc = __builtin_amdgcn_mfma_f32_16x16x32_bf16(fh,  bl, acc, 0, 0, 0);
        d[t] = acc;
    }
    __builtin_amdgcn_wave_barrier();   // feature reads complete before overwrite
    #pragma unroll
    for (int t = 0; t < 4; t++)
        #pragma unroll
        for (int r = 0; r < 4; r++)
            s_pf[q * 4 + r][t * 16 + m] = fmaxf(d[t][r], 0.f);
    __builtin_amdgcn_wave_barrier();
}

// kB: D[p][j] = [pf1[p], v1[vox(p)]] @ W2 via MFMA -> segment max -> out.
// R6: interior lanes rebuild v1 locally; ext lanes read the BOUNDARY-indexed
// seam row (R11): bidx = first-ext ? wave : wave+1 — no voxel map needed.
__global__ __launch_bounds__(256) void kB(const float4* __restrict__ pos4,
                                          const float* __restrict__ e1b,
                                          const int* __restrict__ cellb,
                                          const float4* __restrict__ vmean4,
                                          const v8s* __restrict__ w1frag,
                                          const v8s* __restrict__ w2frag,
                                          const float* __restrict__ v1c,
                                          float* __restrict__ out) {
    __shared__ float s_pf[4][RUN][PSTR];
    int wslot = threadIdx.x >> 6;
    int wave = blockIdx.x * 4 + wslot;
    int j = threadIdx.x & 63;
    int base = wave * RUN;

    PtRegs P = load_pt(pos4, e1b, cellb, vmean4, base, j);

    const int m = j & 15, q = j >> 4;

    const int first = rli(P.vx, 0), last = rli(P.vx, RUN - 1);
    const bool firstExt = (rli(P.vx, 17) == first);
    const bool lastExt  = (rli(P.vx, 16) == last);

    // Per-lane segment bounds for point m (ballot over run boundaries).
    int vx_m = __builtin_amdgcn_ds_bpermute(m << 2, P.vx);
    int vx_prev = __shfl_up(P.vx, 1, 64);
    unsigned long long B =
        __ballot((j < RUN) && ((j == 0) || (P.vx != vx_prev)));
    int s_seg = 63 - __builtin_clzll(B & ((2ULL << m) - 1ULL));
    int e_seg = m + 1 + (int)__builtin_ctzll((B | (1ULL << RUN)) >> (m + 1));
    const bool fext_m = (vx_m == first && firstExt);
    const bool ext_m = fext_m || (vx_m == last && lastExt);
    const int bidx = fext_m ? wave : (wave + 1);   // seam row for this lane

    phase1_mfma(s_pf[wslot], P, w1frag, j);

    // ext lanes: issue seam-row loads now (covered by local loop below)
    float vf[16];
    if (ext_m) {
        const float* vr = v1c + (size_t)bidx * 64 + q * 8;
        #pragma unroll
        for (int c = 0; c < 2; c++)
            #pragma unroll
            for (int i = 0; i < 8; i++) vf[c * 8 + i] = vr[c * 32 + i];
    }

    // A-frags: chunks 0,1 = pf1 rows (lane-distinct LDS reads)
    v8s ah[4], al[4];
    #pragma unroll
    for (int c = 0; c < 2; c++) {
        float f[8];
        #pragma unroll
        for (int i = 0; i < 8; i++) f[i] = s_pf[wslot][m][c * 32 + q * 8 + i];
        split8(f, ah[c], al[c]);
    }
    // interior lanes: v1 row = local segment max over own pf1 (identical set)
    if (!ext_m) {
        #pragma unroll
        for (int i = 0; i < 16; i++) vf[i] = 0.f;
        for (int p = s_seg; p < e_seg; p++) {
            const float* row = s_pf[wslot][p];
            float4 a0 = *(const float4*)&row[q * 8];
            float4 a1 = *(const float4*)&row[q * 8 + 4];
            float4 b0 = *(const float4*)&row[32 + q * 8];
            float4 b1 = *(const float4*)&row[32 + q * 8 + 4];
            vf[0] = fmaxf(vf[0], a0.x);  vf[1] = fmaxf(vf[1], a0.y);
            vf[2] = fmaxf(vf[2], a0.z);  vf[3] = fmaxf(vf[3], a0.w);
            vf[4] = fmaxf(vf[4], a1.x);  vf[5] = fmaxf(vf[5], a1.y);
            vf[6] = fmaxf(vf[6], a1.z);  vf[7] = fmaxf(vf[7], a1.w);
            vf[8] = fmaxf(vf[8], b0.x);  vf[9] = fmaxf(vf[9], b0.y);
            vf[10] = fmaxf(vf[10], b0.z); vf[11] = fmaxf(vf[11], b0.w);
            vf[12] = fmaxf(vf[12], b1.x); vf[13] = fmaxf(vf[13], b1.y);
            vf[14] = fmaxf(vf[14], b1.z); vf[15] = fmaxf(vf[15], b1.w);
        }
    }
    // chunks 2,3 = v1 row (segment-constant: rides inside the acc)
    split8(vf + 0, ah[2], al[2]);
    split8(vf + 8, ah[3], al[3]);
    __builtin_amdgcn_wave_barrier();   // A reads done before D overwrites s_pf

    #pragma unroll
    for (int t = 0; t < 4; t++) {
        v8s bh[4], bl[4];
        #pragma unroll
        for (int c = 0; c < 4; c++) {
            bh[c] = w2frag[((t * 4 + c) * 2 + 0) * 64 + j];
            bl[c] = w2frag[((t * 4 + c) * 2 + 1) * 64 + j];
        }
        v4f acc = {0.f, 0.f, 0.f, 0.f};
        #pragma unroll
        for (int c = 0; c < 4; c++) {
            acc = __builtin_amdgcn_mfma_f32_16x16x32_bf16(ah[c], bh[c], acc, 0, 0, 0);
            acc = __builtin_amdgcn_mfma_f32_16x16x32_bf16(al[c], bh[c], acc, 0, 0, 0);
            acc = __builtin_amdgcn_mfma_f32_16x16x32_bf16(ah[c], bl[c], acc, 0, 0, 0);
        }
        #pragma unroll
        for (int r = 0; r < 4; r++) s_pf[wslot][q * 4 + r][t * 16 + m] = acc[r];
    }
    __builtin_amdgcn_wave_barrier();

    int vprev = first;
    float smax = -3.4e38f;
    for (int p = 0; p < RUN; p++) {
        int vp = rli(P.vx, p);
        if (vp != vprev) {
            float r = fmaxf(smax, 0.f);
            size_t o = (size_t)vprev * 64 + j;
            bool ua = (vprev == first && firstExt) || (vprev == last && lastExt);
            if (ua) atomicMax((int*)out + o, __float_as_int(r));
            else out[o] = r;
            vprev = vp; smax = -3.4e38f;
        }
        smax = fmaxf(smax, s_pf[wslot][p][j]);
    }
    {
        float r = fmaxf(smax, 0.f);
        size_t o = (size_t)vprev * 64 + j;
        bool ua = (vprev == first && firstExt) || (vprev == last && lastExt);
        if (ua) atomicMax((int*)out + o, __float_as_int(r));
        else out[o] = r;
    }
}

extern "C" void kernel_launch(void* const* d_in, const int* in_sizes, int n_in,
                              void* d_out, int out_size, void* d_ws, size_t ws_size,
                              hipStream_t stream) {
    const float* pts = (const float*)d_in[0];
    const float* W1  = (const float*)d_in[1];
    const float* W2  = (const float*)d_in[2];
    float* out = (float*)d_out;

    float4* vmean4 = (float4*)d_ws;                         // CANVAS float4
    float*  v1c    = (float*)(vmean4 + CANVASc);            // NRUNS*64 (6.4 MB)
    float4* pos4   = (float4*)(v1c + (size_t)NRUNS * 64);   // NPTS float4
    float*  e1b    = (float*)(pos4 + NPTS);                 // NPTS
    int*    cellb  = (int*)(e1b + NPTS);                    // NPTS
    int*    rankb  = cellb + NPTS;                          // NPTS
    int*    cellu  = rankb + NPTS;                          // NPTS
    v8s*    w2frag = (v8s*)(cellu + NPTS);                  // 2048 v8s
    v8s*    w1frag = w2frag + 2048;                         // 512 v8s
    int*    cnt    = (int*)(w1frag + 512);                  // CANVAS
    int*    gcur   = cnt + CANVASc;                         // 1
    int*    cursor = gcur + 1;                              // CANVAS

    hipMemsetAsync(cnt, 0, (size_t)(CANVASc + 1) * 4, stream);   // cnt + gcur

    k_stats  <<<GPTS + 5, 256, 0, stream>>>(pts, cnt, rankb, cellu,
                                            W1, W2, w1frag, w2frag);
    k_alloc  <<<GVOX, 256, 0, stream>>>(cnt, cursor, gcur);
    k_scatter<<<GPTS, 256, 0, stream>>>(pts, cursor, rankb, cellu,
                                        pos4, e1b, cellb);
    kV       <<<GVOX + GBND, 256, 0, stream>>>(cnt, cursor, pos4, e1b, cellb,
                                               W1, vmean4, v1c, out);
    kB       <<<NRUNS / 4, 256, 0, stream>>>(pos4, e1b, cellb, vmean4, w1frag,
                                             w2frag, v1c, out);
}